// Round 1
// baseline (3213.948 us; speedup 1.0000x reference)
//
#include <hip/hip_runtime.h>
#include <math.h>

#define HH 512
#define WW 512
#define CC 64
#define NP (HH*WW)

// workspace float offsets
#define OFF_TWC 0            // [512][20] cos(2pi kx w/512)
#define OFF_TWS 10240        // [512][20] sin
#define OFF_THC 20480        // [40][512] cos(2pi ky(m) h/512)
#define OFF_THS 40960        // [40][512] sin
#define OFF_XW  61440        // [C*H][40]  (re,im interleaved per kx)  1310720
#define OFF_XF  1372160      // [800 modes][64 c][2]                   102400
#define OFF_YF  1474560      // [800 modes][64 o][2]                   102400
#define OFF_Z   1576960      // [512 h][64 o][20 kx][2]                1310720
#define OFF_V   2887680      // [64][512][512]                         16777216
#define OFF_VB  19664896     // [64][512][512]                         16777216
// total 36442112 floats = 145.8 MB

__global__ void k_tables(float* __restrict__ ws) {
    int i = blockIdx.x * 256 + threadIdx.x;
    const float c2pi = 6.283185307179586f / 512.0f;
    if (i < 10240) {
        int w = i / 20, kx = i % 20;
        int t = (kx * w) & 511;
        float a = c2pi * (float)t;
        ws[OFF_TWC + i] = cosf(a);
        ws[OFF_TWS + i] = sinf(a);
    } else if (i < 30720) {
        int j = i - 10240;
        int m = j / 512, h = j & 511;
        int ky = (m < 20) ? m : (472 + m);   // 492..511 for m=20..39
        int t = (ky * h) & 511;
        float a = c2pi * (float)t;
        ws[OFF_THC + j] = cosf(a);
        ws[OFF_THS + j] = sinf(a);
    }
}

__global__ void k_fc0(const float* __restrict__ x, const float* __restrict__ w,
                      const float* __restrict__ b, float* __restrict__ v) {
    int p = blockIdx.x * 256 + threadIdx.x;
    float x0 = x[p*3], x1 = x[p*3+1], x2 = x[p*3+2];
    for (int c = 0; c < 64; ++c) {
        v[c*NP + p] = w[c*3]*x0 + w[c*3+1]*x1 + w[c*3+2]*x2 + b[c];
    }
}

// xw[r][j]: j = kx*2 + (0:re,1:im);  re = sum_w v*cos, im = -sum_w v*sin
__global__ void k_f1(const float* __restrict__ v, float* __restrict__ ws) {
    int r = blockIdx.x;          // c*512 + h
    int j = threadIdx.x;         // 0..63, active < 40
    if (j >= 40) return;
    const float* __restrict__ row = v + (size_t)r * 512;
    const float* __restrict__ tbl = ws + ((j & 1) ? OFF_TWS : OFF_TWC) + (j >> 1);
    float acc = 0.f;
    #pragma unroll 8
    for (int w = 0; w < 512; ++w)
        acc += row[w] * tbl[w*20];
    if (j & 1) acc = -acc;
    ws[OFF_XW + (size_t)r*40 + j] = acc;
}

// xf[mode][c][2], mode = m*20+kx ; xf = sum_h xw * e^{-i 2pi ky h /H}
__global__ void k_f2(float* __restrict__ ws) {
    int b = blockIdx.x;          // c*20 + kx
    int c = b / 20, kx = b % 20;
    int m = threadIdx.x;         // ky-slot 0..39
    if (m >= 40) return;
    const float* __restrict__ xw  = ws + OFF_XW + (size_t)(c*512)*40 + 2*kx;
    const float* __restrict__ thc = ws + OFF_THC + m*512;
    const float* __restrict__ ths = ws + OFF_THS + m*512;
    float ar = 0.f, ai = 0.f;
    #pragma unroll 4
    for (int h = 0; h < 512; ++h) {
        float a = xw[h*40], bb = xw[h*40+1];
        float cc = thc[h],  ss = ths[h];
        ar += a*cc + bb*ss;      // (a+bi)(c - i s)
        ai += bb*cc - a*ss;
    }
    int mode = m*20 + kx;
    ws[OFF_XF + mode*128 + c*2]     = ar;
    ws[OFF_XF + mode*128 + c*2 + 1] = ai;
}

// out_ft[mode][o] = sum_i xf[mode][i] * (wr + i wi)[i][o][x][y]
__global__ void k_mix(const float* __restrict__ w1r, const float* __restrict__ w1i,
                      const float* __restrict__ w2r, const float* __restrict__ w2i,
                      float* __restrict__ ws) {
    __shared__ float xf[128];
    int mode = blockIdx.x;       // m*20+kx
    int o = threadIdx.x;
    int m = mode / 20, kx = mode % 20;
    xf[o]      = ws[OFF_XF + mode*128 + o];
    xf[o + 64] = ws[OFF_XF + mode*128 + o + 64];
    __syncthreads();
    const float* wr; const float* wi; int x;
    if (m < 20) { wr = w1r; wi = w1i; x = m; }
    else        { wr = w2r; wi = w2i; x = m - 20; }
    int wof = o*400 + x*20 + kx;
    float ar = 0.f, ai = 0.f;
    #pragma unroll 4
    for (int i = 0; i < 64; ++i) {
        float xr = xf[2*i], xi = xf[2*i+1];
        float a = wr[(size_t)i*25600 + wof], bb = wi[(size_t)i*25600 + wof];
        ar += xr*a - xi*bb;
        ai += xr*bb + xi*a;
    }
    ws[OFF_YF + mode*128 + o*2]     = ar;
    ws[OFF_YF + mode*128 + o*2 + 1] = ai;
}

// Z[h][o][kx] = scale(kx)/(H) * sum_m Y[m][kx][o] * e^{+i 2pi ky(m) h/H}, scale folded
__global__ void k_i1(float* __restrict__ ws) {
    int bid = blockIdx.x;                    // 512*5
    int h = bid / 5;
    int t = (bid % 5) * 256 + threadIdx.x;   // 0..1279
    int o = t / 20, kx = t % 20;
    const float* __restrict__ yf  = ws + OFF_YF + kx*128 + o*2;
    const float* __restrict__ thc = ws + OFF_THC + h;
    const float* __restrict__ ths = ws + OFF_THS + h;
    float zr = 0.f, zi = 0.f;
    #pragma unroll 4
    for (int m = 0; m < 40; ++m) {
        float yr = yf[m*2560], yi = yf[m*2560 + 1];
        float cc = thc[m*512], ss = ths[m*512];
        zr += yr*cc - yi*ss;                 // (yr+i yi)(c + i s)
        zi += yr*ss + yi*cc;
    }
    float sc = (kx == 0 ? 1.0f : 2.0f) * (1.0f/262144.0f);
    ws[OFF_Z + ((size_t)h*64 + o)*40 + 2*kx]     = zr*sc;
    ws[OFF_Z + ((size_t)h*64 + o)*40 + 2*kx + 1] = zi*sc;
}

// v_out[o][h][w] = tanh( sum_c cw[o][c] v[c][h][w] + cb[o]
//                        + sum_kx Zr[h][o][kx] cos(2pi kx w/W) - Zi[h][o][kx] sin(...) )
__global__ __launch_bounds__(256) void k_sct(const float* __restrict__ v,
    const float* __restrict__ cw, const float* __restrict__ cb,
    const float* __restrict__ ws, float* __restrict__ vout) {
    __shared__ float cws[4096];
    __shared__ float zrow[2560];
    __shared__ float cbs[64];
    int bid = blockIdx.x;           // 512*2
    int h = bid >> 1;
    int w = ((bid & 1) << 8) + threadIdx.x;
    for (int i = threadIdx.x; i < 4096; i += 256) cws[i] = cw[i];
    for (int i = threadIdx.x; i < 2560; i += 256) zrow[i] = ws[OFF_Z + (size_t)h*2560 + i];
    if (threadIdx.x < 64) cbs[threadIdx.x] = cb[threadIdx.x];
    __syncthreads();
    float twc[20], tws[20];
    #pragma unroll
    for (int k = 0; k < 20; ++k) {
        twc[k] = ws[OFF_TWC + w*20 + k];
        tws[k] = ws[OFF_TWS + w*20 + k];
    }
    float acc[64];
    #pragma unroll
    for (int o = 0; o < 64; ++o) acc[o] = cbs[o];
    const float* __restrict__ vp = v + (size_t)h*512 + w;
    for (int c = 0; c < 64; ++c) {
        float val = vp[(size_t)c*NP];
        #pragma unroll
        for (int o = 0; o < 64; ++o) acc[o] += cws[o*64 + c] * val;
    }
    float* __restrict__ vo = vout + (size_t)h*512 + w;
    #pragma unroll
    for (int o = 0; o < 64; ++o) {
        float s = 0.f;
        #pragma unroll
        for (int k = 0; k < 20; ++k)
            s += zrow[o*40 + 2*k]*twc[k] - zrow[o*40 + 2*k + 1]*tws[k];
        vo[(size_t)o*NP] = tanhf(acc[o] + s);
    }
}

__global__ __launch_bounds__(256) void k_fc12(const float* __restrict__ v,
    const float* __restrict__ w1, const float* __restrict__ b1,
    const float* __restrict__ w2, const float* __restrict__ b2,
    float* __restrict__ out) {
    __shared__ float w1s[8192];
    __shared__ float b1s[128], w2s[128];
    int p = blockIdx.x * 256 + threadIdx.x;
    for (int i = threadIdx.x; i < 8192; i += 256) w1s[i] = w1[i];
    if (threadIdx.x < 128) { b1s[threadIdx.x] = b1[threadIdx.x]; w2s[threadIdx.x] = w2[threadIdx.x]; }
    __syncthreads();
    float acc[128];
    #pragma unroll
    for (int f = 0; f < 128; ++f) acc[f] = 0.f;
    const float* __restrict__ vp = v + p;
    for (int c = 0; c < 64; ++c) {
        float val = vp[(size_t)c*NP];
        #pragma unroll
        for (int f = 0; f < 128; ++f) acc[f] += w1s[f*64 + c] * val;
    }
    float o = b2[0];
    #pragma unroll
    for (int f = 0; f < 128; ++f) o += w2s[f] * tanhf(acc[f] + b1s[f]);
    out[p] = o;
}

extern "C" void kernel_launch(void* const* d_in, const int* in_sizes, int n_in,
                              void* d_out, int out_size, void* d_ws, size_t ws_size,
                              hipStream_t stream) {
    const float* x     = (const float*)d_in[0];
    const float* fc0w  = (const float*)d_in[1];
    const float* fc0b  = (const float*)d_in[2];
    const float* sw1r  = (const float*)d_in[3];
    const float* sw1i  = (const float*)d_in[4];
    const float* sw2r  = (const float*)d_in[5];
    const float* sw2i  = (const float*)d_in[6];
    const float* convw = (const float*)d_in[7];
    const float* convb = (const float*)d_in[8];
    const float* fc1w  = (const float*)d_in[9];
    const float* fc1b  = (const float*)d_in[10];
    const float* fc2w  = (const float*)d_in[11];
    const float* fc2b  = (const float*)d_in[12];
    float* ws  = (float*)d_ws;
    float* out = (float*)d_out;

    hipLaunchKernelGGL(k_tables, dim3(120), dim3(256), 0, stream, ws);
    float* v  = ws + OFF_V;
    float* vb = ws + OFF_VB;
    hipLaunchKernelGGL(k_fc0, dim3(1024), dim3(256), 0, stream, x, fc0w, fc0b, v);
    for (int L = 0; L < 4; ++L) {
        size_t so = (size_t)L * 64 * 64 * 400;
        hipLaunchKernelGGL(k_f1, dim3(32768), dim3(64), 0, stream, v, ws);
        hipLaunchKernelGGL(k_f2, dim3(1280), dim3(64), 0, stream, ws);
        hipLaunchKernelGGL(k_mix, dim3(800), dim3(64), 0, stream,
                           sw1r + so, sw1i + so, sw2r + so, sw2i + so, ws);
        hipLaunchKernelGGL(k_i1, dim3(2560), dim3(256), 0, stream, ws);
        hipLaunchKernelGGL(k_sct, dim3(1024), dim3(256), 0, stream,
                           v, convw + (size_t)L*4096, convb + (size_t)L*64, ws, vb);
        float* t = v; v = vb; vb = t;
    }
    hipLaunchKernelGGL(k_fc12, dim3(1024), dim3(256), 0, stream,
                       v, fc1w, fc1b, fc2w, fc2b, out);
}

// Round 2
// 1210.616 us; speedup vs baseline: 2.6548x; 2.6548x over previous
//
#include <hip/hip_runtime.h>
#include <math.h>

typedef unsigned short u16;
typedef __attribute__((ext_vector_type(8))) short bf16x8;
typedef __attribute__((ext_vector_type(4))) float f32x4;

#define NP (512*512)
#define MFMA16 __builtin_amdgcn_mfma_f32_16x16x32_bf16

// workspace byte offsets (all 16B-aligned)
#define OFF_THC 0u          // fp32 [40][512]
#define OFF_THS 81920u      // fp32 [40][512]
#define OFF_XW  163840u     // fp32 [32768][48]
#define OFF_XF  6455296u    // fp32 [800][128]
#define OFF_YF  6864896u    // fp32 [800][128]
#define OFF_TWH 7274496u    // bf16 f1 B-frags [16ks][3nt][64][8]
#define OFF_TWL 7323648u
#define OFF_T2H 7372800u    // bf16 sct spectral B-frags [32wt][2ks][64][8]
#define OFF_T2L 7438336u
#define OFF_ZH  7503872u    // bf16 [512][64][64]
#define OFF_ZL  11698176u
#define OFF_VH  15892480u   // bf16 [64][NP]
#define OFF_VL  49446912u   // total 83.0 MB

__device__ __forceinline__ u16 brnd(float x){
    unsigned u = __float_as_uint(x);
    unsigned r = (u + 0x7FFFu + ((u>>16)&1u)) >> 16;
    return (u16)r;
}
__device__ __forceinline__ float fbf(u16 h){ return __uint_as_float(((unsigned)h)<<16); }
__device__ __forceinline__ void bsplit(float x, u16& h, u16& l){
    h = brnd(x); l = brnd(x - fbf(h));
}
__device__ __forceinline__ float tanhfast(float x){
    x = fminf(10.f, fmaxf(-10.f, x));
    float e = __expf(2.f*x);
    return (e-1.f)/(e+1.f);
}

// ---- tables: fp32 H-dir twiddles + fragment-ordered bf16 split DFT matrices
__global__ void k_tables(char* wsb){
    int i = blockIdx.x*256 + threadIdx.x;
    const float c2pi = 6.283185307179586f/512.0f;
    if (i < 20480){                      // THC/THS [40][512]
        int m = i>>9, h = i&511;
        int ky = (m<20) ? m : (472+m);
        float a = c2pi*(float)((ky*h)&511);
        ((float*)(wsb+OFF_THC))[i] = cosf(a);
        ((float*)(wsb+OFF_THS))[i] = sinf(a);
    } else if (i < 45056){               // TW frags (f1 B-role): B[k=w][n=j]
        int j2 = i - 20480;
        int e = j2&7, lane = (j2>>3)&63, g = j2>>9;
        int nt = g%3, kk = g/3;
        int k = kk*32 + ((lane>>4)<<3) + e;    // w 0..511
        int n = nt*16 + (lane&15);             // j 0..47
        float v = 0.f;
        if (n < 40){ int kx = n>>1; float a = c2pi*(float)((kx*k)&511);
                     v = (n&1) ? -sinf(a) : cosf(a); }
        u16 hh, ll; bsplit(v, hh, ll);
        ((u16*)(wsb+OFF_TWH))[j2] = hh; ((u16*)(wsb+OFF_TWL))[j2] = ll;
    } else if (i < 77824){               // T2 frags (sct B-role): B[k=j][n=w]
        int j2 = i - 45056;
        int e = j2&7, lane = (j2>>3)&63, g = j2>>9;
        int ks = g&1, wt = g>>1;
        int j = ks*32 + ((lane>>4)<<3) + e;    // j 0..63
        int w = wt*16 + (lane&15);             // w 0..511
        float v = 0.f;
        if (j < 40){ int kx = j>>1; float a = c2pi*(float)((kx*w)&511);
                     v = (j&1) ? -sinf(a) : cosf(a); }
        u16 hh, ll; bsplit(v, hh, ll);
        ((u16*)(wsb+OFF_T2H))[j2] = hh; ((u16*)(wsb+OFF_T2L))[j2] = ll;
    }
}

__global__ void k_fc0(const float* __restrict__ x, const float* __restrict__ w,
                      const float* __restrict__ b, u16* __restrict__ vh, u16* __restrict__ vl){
    int p = blockIdx.x*256 + threadIdx.x;
    float x0 = x[p*3], x1 = x[p*3+1], x2 = x[p*3+2];
    for (int c = 0; c < 64; ++c){
        float val = w[c*3]*x0 + w[c*3+1]*x1 + w[c*3+2]*x2 + b[c];
        u16 hh, ll; bsplit(val, hh, ll);
        vh[(size_t)c*NP + p] = hh; vl[(size_t)c*NP + p] = ll;
    }
}

// ---- F1: xw[32768 rows][48] = v[row][512w] x TW[512][48], MFMA split
__global__ __launch_bounds__(256) void k_f1(const u16* __restrict__ vh, const u16* __restrict__ vl,
    const u16* __restrict__ twh, const u16* __restrict__ twl, float* __restrict__ xw){
    int lane = threadIdx.x & 63, wv = threadIdx.x >> 6;
    int rowa = blockIdx.x*64 + wv*16 + (lane&15);
    const u16* ah = vh + (size_t)rowa*512 + ((lane>>4)<<3);
    const u16* al = vl + (size_t)rowa*512 + ((lane>>4)<<3);
    f32x4 acc[3];
    #pragma unroll
    for (int nt = 0; nt < 3; ++nt) acc[nt] = (f32x4){0.f,0.f,0.f,0.f};
    for (int kk = 0; kk < 16; ++kk){
        bf16x8 Ah = *reinterpret_cast<const bf16x8*>(ah + kk*32);
        bf16x8 Al = *reinterpret_cast<const bf16x8*>(al + kk*32);
        #pragma unroll
        for (int nt = 0; nt < 3; ++nt){
            size_t bo = ((size_t)(kk*3+nt)*64 + lane)*8;
            bf16x8 Bh = *reinterpret_cast<const bf16x8*>(twh + bo);
            bf16x8 Bl = *reinterpret_cast<const bf16x8*>(twl + bo);
            acc[nt] = MFMA16(Ah, Bh, acc[nt], 0,0,0);
            acc[nt] = MFMA16(Ah, Bl, acc[nt], 0,0,0);
            acc[nt] = MFMA16(Al, Bh, acc[nt], 0,0,0);
        }
    }
    int r0 = blockIdx.x*64 + wv*16 + ((lane>>4)<<2);
    int col = lane&15;
    #pragma unroll
    for (int nt = 0; nt < 3; ++nt)
        #pragma unroll
        for (int rg = 0; rg < 4; ++rg)
            xw[(size_t)(r0+rg)*48 + nt*16 + col] = acc[nt][rg];
}

// ---- F2: H-direction forward DFT (VALU, small)
__global__ void k_f2(const float* __restrict__ xw, const float* __restrict__ thcb,
                     const float* __restrict__ thsb, float* __restrict__ xf){
    int b = blockIdx.x; int c = b/20, kx = b%20;
    int m = threadIdx.x; if (m >= 40) return;
    const float* xwp = xw + (size_t)(c*512)*48 + 2*kx;
    const float* thc = thcb + m*512;
    const float* ths = thsb + m*512;
    float ar=0.f, ai=0.f, ar2=0.f, ai2=0.f;
    for (int h = 0; h < 512; h += 2){
        float a = xwp[(size_t)h*48], bb = xwp[(size_t)h*48+1];
        float cc = thc[h], ss = ths[h];
        ar += a*cc + bb*ss; ai += bb*cc - a*ss;
        float a2 = xwp[(size_t)(h+1)*48], b2 = xwp[(size_t)(h+1)*48+1];
        float c2 = thc[h+1], s2 = ths[h+1];
        ar2 += a2*c2 + b2*s2; ai2 += b2*c2 - a2*s2;
    }
    int mode = m*20 + kx;
    xf[mode*128 + c*2]   = ar + ar2;
    xf[mode*128 + c*2+1] = ai + ai2;
}

// ---- mode mixing (VALU; weight-traffic bound)
__global__ void k_mix(const float* __restrict__ w1r, const float* __restrict__ w1i,
                      const float* __restrict__ w2r, const float* __restrict__ w2i,
                      const float* __restrict__ xf, float* __restrict__ yf){
    __shared__ float xs[128];
    int mode = blockIdx.x;
    int o = threadIdx.x;
    int m = mode/20, kx = mode%20;
    xs[o]    = xf[mode*128 + o];
    xs[o+64] = xf[mode*128 + o + 64];
    __syncthreads();
    const float* wr; const float* wi; int xr_;
    if (m < 20){ wr = w1r; wi = w1i; xr_ = m; }
    else       { wr = w2r; wi = w2i; xr_ = m - 20; }
    int wof = o*400 + xr_*20 + kx;
    float ar = 0.f, ai = 0.f;
    #pragma unroll 4
    for (int i = 0; i < 64; ++i){
        float xr = xs[2*i], xi = xs[2*i+1];
        float a = wr[(size_t)i*25600 + wof], bb = wi[(size_t)i*25600 + wof];
        ar += xr*a - xi*bb;
        ai += xr*bb + xi*a;
    }
    yf[mode*128 + o*2]   = ar;
    yf[mode*128 + o*2+1] = ai;
}

// ---- I1: inverse H-DFT -> Z, written pre-split bf16 in [h][o][64] (j padded 0)
__global__ void k_i1(const float* __restrict__ yf, const float* __restrict__ thcb,
                     const float* __restrict__ thsb, u16* __restrict__ zh, u16* __restrict__ zl){
    int bid = blockIdx.x;
    int h = bid >> 3;
    int t = threadIdx.x;
    int s = t & 31;
    int o = ((bid & 7) << 3) + (t >> 5);
    size_t zo = ((size_t)h*64 + o)*64 + 2*s;
    if (s >= 20){ zh[zo]=0; zh[zo+1]=0; zl[zo]=0; zl[zo+1]=0; return; }
    const float* yp  = yf + s*128 + o*2;
    const float* thc = thcb + h;
    const float* ths = thsb + h;
    float zr = 0.f, zi = 0.f;
    #pragma unroll 4
    for (int m = 0; m < 40; ++m){
        float yr = yp[(size_t)m*2560], yi = yp[(size_t)m*2560+1];
        float cc = thc[(size_t)m*512], ss = ths[(size_t)m*512];
        zr += yr*cc - yi*ss;
        zi += yr*ss + yi*cc;
    }
    float sc = (s==0 ? 1.f : 2.f) * (1.f/262144.f);
    u16 hh, ll;
    bsplit(zr*sc, hh, ll); zh[zo] = hh;   zl[zo] = ll;
    bsplit(zi*sc, hh, ll); zh[zo+1] = hh; zl[zo+1] = ll;
}

// ---- SCT: conv(64x64) + inverse-W spectral + bias + tanh, MFMA, in-place
#define LST 74  // LDS row stride (u16): 37 dwords, odd => conflict-free columns
__global__ __launch_bounds__(256) void k_sct(u16* __restrict__ vh, u16* __restrict__ vl,
    const float* __restrict__ cw, const float* __restrict__ cb,
    const u16* __restrict__ zfh, const u16* __restrict__ zfl,
    const u16* __restrict__ t2h, const u16* __restrict__ t2l){
    __shared__ u16 lh[64*LST];
    __shared__ u16 ll[64*LST];
    int tid = threadIdx.x, lane = tid & 63, wv = tid >> 6;
    int h = blockIdx.x >> 3, pb = (blockIdx.x & 7) * 64;
    size_t gbase = (size_t)h*512 + pb;
    for (int c = wv; c < 64; c += 4){
        lh[c*LST + lane] = vh[(size_t)c*NP + gbase + lane];
        ll[c*LST + lane] = vl[(size_t)c*NP + gbase + lane];
    }
    __syncthreads();
    f32x4 acc[4];
    #pragma unroll
    for (int mt = 0; mt < 4; ++mt) acc[mt] = (f32x4){0.f,0.f,0.f,0.f};
    int col = wv*16 + (lane&15);
    // conv: A = W[o][c] (global fp32 split), B = v[c][p] (LDS)
    #pragma unroll
    for (int ks = 0; ks < 2; ++ks){
        bf16x8 Bh, Bl;
        #pragma unroll
        for (int e = 0; e < 8; ++e){
            int c = ks*32 + ((lane>>4)<<3) + e;
            Bh[e] = (short)lh[c*LST + col];
            Bl[e] = (short)ll[c*LST + col];
        }
        #pragma unroll
        for (int mt = 0; mt < 4; ++mt){
            const float* wp = cw + (size_t)(mt*16 + (lane&15))*64 + ks*32 + ((lane>>4)<<3);
            float4 a0 = *reinterpret_cast<const float4*>(wp);
            float4 a1 = *reinterpret_cast<const float4*>(wp+4);
            float wf[8] = {a0.x,a0.y,a0.z,a0.w,a1.x,a1.y,a1.z,a1.w};
            bf16x8 Ah, Al;
            #pragma unroll
            for (int e = 0; e < 8; ++e){ u16 hh, l2; bsplit(wf[e], hh, l2);
                                         Ah[e]=(short)hh; Al[e]=(short)l2; }
            acc[mt] = MFMA16(Ah, Bh, acc[mt], 0,0,0);
            acc[mt] = MFMA16(Ah, Bl, acc[mt], 0,0,0);
            acc[mt] = MFMA16(Al, Bh, acc[mt], 0,0,0);
        }
    }
    // spectral: A = Z[h][o][j] (global bf16 frags), B = T2 frags
    int wt = (pb>>4) + wv;
    #pragma unroll
    for (int ks = 0; ks < 2; ++ks){
        size_t bo = ((size_t)(wt*2+ks)*64 + lane)*8;
        bf16x8 Bh = *reinterpret_cast<const bf16x8*>(t2h + bo);
        bf16x8 Bl = *reinterpret_cast<const bf16x8*>(t2l + bo);
        #pragma unroll
        for (int mt = 0; mt < 4; ++mt){
            size_t ao = ((size_t)h*64 + mt*16 + (lane&15))*64 + ks*32 + ((lane>>4)<<3);
            bf16x8 Ah = *reinterpret_cast<const bf16x8*>(zfh + ao);
            bf16x8 Al = *reinterpret_cast<const bf16x8*>(zfl + ao);
            acc[mt] = MFMA16(Ah, Bh, acc[mt], 0,0,0);
            acc[mt] = MFMA16(Ah, Bl, acc[mt], 0,0,0);
            acc[mt] = MFMA16(Al, Bh, acc[mt], 0,0,0);
        }
    }
    // epilogue: tanh + split-write (in-place safe: tile fully staged)
    size_t pg = gbase + wv*16 + (lane&15);
    #pragma unroll
    for (int mt = 0; mt < 4; ++mt)
        #pragma unroll
        for (int rg = 0; rg < 4; ++rg){
            int o = mt*16 + ((lane>>4)<<2) + rg;
            float val = tanhfast(acc[mt][rg] + cb[o]);
            u16 hh, l2; bsplit(val, hh, l2);
            vh[(size_t)o*NP + pg] = hh;
            vl[(size_t)o*NP + pg] = l2;
        }
}

// ---- fc1 (MFMA) + tanh + fc2 fused
__global__ __launch_bounds__(256) void k_fc12(const u16* __restrict__ vh, const u16* __restrict__ vl,
    const float* __restrict__ w1, const float* __restrict__ b1,
    const float* __restrict__ w2, const float* __restrict__ b2, float* __restrict__ out){
    __shared__ u16 lh[64*LST];
    __shared__ u16 ll[64*LST];
    int tid = threadIdx.x, lane = tid & 63, wv = tid >> 6;
    size_t pb = (size_t)blockIdx.x * 64;
    for (int c = wv; c < 64; c += 4){
        lh[c*LST + lane] = vh[(size_t)c*NP + pb + lane];
        ll[c*LST + lane] = vl[(size_t)c*NP + pb + lane];
    }
    __syncthreads();
    f32x4 acc[8];
    #pragma unroll
    for (int mt = 0; mt < 8; ++mt) acc[mt] = (f32x4){0.f,0.f,0.f,0.f};
    int col = wv*16 + (lane&15);
    #pragma unroll
    for (int ks = 0; ks < 2; ++ks){
        bf16x8 Bh, Bl;
        #pragma unroll
        for (int e = 0; e < 8; ++e){
            int c = ks*32 + ((lane>>4)<<3) + e;
            Bh[e] = (short)lh[c*LST + col];
            Bl[e] = (short)ll[c*LST + col];
        }
        #pragma unroll
        for (int mt = 0; mt < 8; ++mt){
            const float* wp = w1 + (size_t)(mt*16 + (lane&15))*64 + ks*32 + ((lane>>4)<<3);
            float4 a0 = *reinterpret_cast<const float4*>(wp);
            float4 a1 = *reinterpret_cast<const float4*>(wp+4);
            float wf[8] = {a0.x,a0.y,a0.z,a0.w,a1.x,a1.y,a1.z,a1.w};
            bf16x8 Ah, Al;
            #pragma unroll
            for (int e = 0; e < 8; ++e){ u16 hh, l2; bsplit(wf[e], hh, l2);
                                         Ah[e]=(short)hh; Al[e]=(short)l2; }
            acc[mt] = MFMA16(Ah, Bh, acc[mt], 0,0,0);
            acc[mt] = MFMA16(Ah, Bl, acc[mt], 0,0,0);
            acc[mt] = MFMA16(Al, Bh, acc[mt], 0,0,0);
        }
    }
    // lane holds H[f = mt*16+4*(lane>>4)+rg][p = pb+wv*16+(lane&15)]
    float s = 0.f;
    #pragma unroll
    for (int mt = 0; mt < 8; ++mt)
        #pragma unroll
        for (int rg = 0; rg < 4; ++rg){
            int f = mt*16 + ((lane>>4)<<2) + rg;
            s += w2[f] * tanhfast(acc[mt][rg] + b1[f]);
        }
    s += __shfl_xor(s, 16);
    s += __shfl_xor(s, 32);
    if (lane < 16) out[pb + wv*16 + lane] = s + b2[0];
}

extern "C" void kernel_launch(void* const* d_in, const int* in_sizes, int n_in,
                              void* d_out, int out_size, void* d_ws, size_t ws_size,
                              hipStream_t stream) {
    const float* x     = (const float*)d_in[0];
    const float* fc0w  = (const float*)d_in[1];
    const float* fc0b  = (const float*)d_in[2];
    const float* sw1r  = (const float*)d_in[3];
    const float* sw1i  = (const float*)d_in[4];
    const float* sw2r  = (const float*)d_in[5];
    const float* sw2i  = (const float*)d_in[6];
    const float* convw = (const float*)d_in[7];
    const float* convb = (const float*)d_in[8];
    const float* fc1w  = (const float*)d_in[9];
    const float* fc1b  = (const float*)d_in[10];
    const float* fc2w  = (const float*)d_in[11];
    const float* fc2b  = (const float*)d_in[12];
    char* wsb = (char*)d_ws;
    float* out = (float*)d_out;

    float* thc = (float*)(wsb + OFF_THC);
    float* ths = (float*)(wsb + OFF_THS);
    float* xw  = (float*)(wsb + OFF_XW);
    float* xf  = (float*)(wsb + OFF_XF);
    float* yf  = (float*)(wsb + OFF_YF);
    u16* twh = (u16*)(wsb + OFF_TWH);
    u16* twl = (u16*)(wsb + OFF_TWL);
    u16* t2h = (u16*)(wsb + OFF_T2H);
    u16* t2l = (u16*)(wsb + OFF_T2L);
    u16* zh  = (u16*)(wsb + OFF_ZH);
    u16* zl  = (u16*)(wsb + OFF_ZL);
    u16* vh  = (u16*)(wsb + OFF_VH);
    u16* vl  = (u16*)(wsb + OFF_VL);

    k_tables<<<304, 256, 0, stream>>>(wsb);
    k_fc0<<<1024, 256, 0, stream>>>(x, fc0w, fc0b, vh, vl);
    for (int L = 0; L < 4; ++L){
        size_t so = (size_t)L * 64 * 64 * 400;
        k_f1<<<512, 256, 0, stream>>>(vh, vl, twh, twl, xw);
        k_f2<<<1280, 64, 0, stream>>>(xw, thc, ths, xf);
        k_mix<<<800, 64, 0, stream>>>(sw1r+so, sw1i+so, sw2r+so, sw2i+so, xf, yf);
        k_i1<<<4096, 256, 0, stream>>>(yf, thc, ths, zh, zl);
        k_sct<<<4096, 256, 0, stream>>>(vh, vl, convw + (size_t)L*4096,
                                        convb + (size_t)L*64, zh, zl, t2h, t2l);
    }
    k_fc12<<<4096, 256, 0, stream>>>(vh, vl, fc1w, fc1b, fc2w, fc2b, out);
}

// Round 4
// 806.158 us; speedup vs baseline: 3.9867x; 1.5017x over previous
//
#include <hip/hip_runtime.h>
#include <math.h>

typedef unsigned short u16;
typedef __attribute__((ext_vector_type(8))) short short8;
typedef __attribute__((ext_vector_type(8))) short bf16x8;
typedef __attribute__((ext_vector_type(4))) unsigned short us4;
typedef __attribute__((ext_vector_type(2))) unsigned short us2;
typedef __attribute__((ext_vector_type(4))) float f32x4;

#define NP (512*512)
#define MFMA16 __builtin_amdgcn_mfma_f32_16x16x32_bf16

// ---- workspace byte offsets (all 256-aligned) ----
#define TWH   0u         // u16 f1 B-frags [kk16][nt3][lane64][e8]
#define TWL   49152u
#define T2H   98304u     // u16 sct spectral B-frags [wt32][ks2][lane64][e8]
#define T2L   163840u
#define THC2H 229376u    // u16 f2 A [m48][h512]
#define THC2L 278528u
#define THS2H 327680u
#define THS2L 376832u
#define THCAH 425984u    // u16 i1 A [h512][m64]
#define THCAL 491520u
#define THSAH 557056u
#define THSAL 622592u
#define THSNH 688128u
#define THSNL 753664u
#define CFH   819200u    // u16 conv frags [L4][ks2][mt4][lane64][e8]
#define CFL   851968u
#define F1H   884736u    // u16 fc1 frags [ks2][mt8][lane64][e8]
#define F1L   901120u
#define XWH   917504u    // u16 [j48][c64][h512]
#define XWL   4063232u
#define XFP   7208960u   // f32 [kh2][c64][mode800*2]
#define YPART 8028160u   // f32 [iseg2][mode800][o64][2]
#define YRH   8847360u   // u16 [kx20][o64][m64]
#define YRL   9011200u
#define YIH   9175040u
#define YIL   9338880u
#define ZH    9502720u   // u16 [h512][o64][j64]
#define ZL    13697024u
#define VH    17891328u  // u16 [c64][NP]
#define VL    51445760u  // end 85000192

__device__ __forceinline__ u16 brnd(float x){
    unsigned u = __float_as_uint(x);
    unsigned r = (u + 0x7FFFu + ((u>>16)&1u)) >> 16;
    return (u16)r;
}
__device__ __forceinline__ float fbf(u16 h){ return __uint_as_float(((unsigned)h)<<16); }
__device__ __forceinline__ void bsplit(float x, u16& h, u16& l){
    h = brnd(x); l = brnd(x - fbf(h));
}
__device__ __forceinline__ float tanhfast(float x){
    x = fminf(10.f, fmaxf(-10.f, x));
    float e = __expf(2.f*x);
    return (e-1.f)/(e+1.f);
}

// ================= tables =================
__global__ void k_tables(char* wsb){
    int i = blockIdx.x*256 + threadIdx.x;
    const float c2pi = 6.283185307179586f/512.0f;
    if (i < 24576){                         // TW
        int e=i&7, lane=(i>>3)&63, g=i>>9; int nt=g%3;
        int k = (g/3)*32 + ((lane>>4)<<3) + e;
        int n = nt*16 + (lane&15);
        float v=0.f;
        if(n<40){int kx=n>>1; float a=c2pi*(float)((kx*k)&511); v=(n&1)?-sinf(a):cosf(a);}
        u16 h,l; bsplit(v,h,l);
        ((u16*)(wsb+TWH))[i]=h; ((u16*)(wsb+TWL))[i]=l;
    } else if (i < 57344){                  // T2
        int j2=i-24576;
        int e=j2&7, lane=(j2>>3)&63, g=j2>>9; int ks=g&1, wt=g>>1;
        int j = ks*32 + ((lane>>4)<<3) + e;
        int w = wt*16 + (lane&15);
        float v=0.f;
        if(j<40){int kx=j>>1; float a=c2pi*(float)((kx*w)&511); v=(j&1)?-sinf(a):cosf(a);}
        u16 h,l; bsplit(v,h,l);
        ((u16*)(wsb+T2H))[j2]=h; ((u16*)(wsb+T2L))[j2]=l;
    } else if (i < 81920){                  // f2 A [m48][h512]
        int j2 = i-57344;
        int m=j2>>9, hh=j2&511;
        float vc=0.f,vs=0.f;
        if(m<40){int ky=(m<20)?m:(472+m); float a=c2pi*(float)((ky*hh)&511); vc=cosf(a); vs=sinf(a);}
        u16 h,l;
        bsplit(vc,h,l); ((u16*)(wsb+THC2H))[j2]=h; ((u16*)(wsb+THC2L))[j2]=l;
        bsplit(vs,h,l); ((u16*)(wsb+THS2H))[j2]=h; ((u16*)(wsb+THS2L))[j2]=l;
    } else if (i < 114688){                 // i1 A [h512][m64]
        int j2 = i-81920;
        int hh=j2>>6, m=j2&63;
        float vc=0.f,vs=0.f;
        if(m<40){int ky=(m<20)?m:(472+m); float a=c2pi*(float)((ky*hh)&511); vc=cosf(a); vs=sinf(a);}
        u16 h,l;
        bsplit(vc,h,l);  ((u16*)(wsb+THCAH))[j2]=h; ((u16*)(wsb+THCAL))[j2]=l;
        bsplit(vs,h,l);  ((u16*)(wsb+THSAH))[j2]=h; ((u16*)(wsb+THSAL))[j2]=l;
        bsplit(-vs,h,l); ((u16*)(wsb+THSNH))[j2]=h; ((u16*)(wsb+THSNL))[j2]=l;
    }
}

// ================= weight fragment prep =================
__global__ void k_wprep(const float* __restrict__ convw, const float* __restrict__ fc1w, char* wsb){
    int i = blockIdx.x*256 + threadIdx.x;
    if (i < 16384){
        int e=i&7, lane=(i>>3)&63, g=i>>9;
        int mt=g&3, ks=(g>>2)&1, L=g>>3;
        int o = mt*16+(lane&15), c = ks*32+((lane>>4)<<3)+e;
        float v = convw[L*4096 + o*64 + c];
        u16 h,l; bsplit(v,h,l);
        ((u16*)(wsb+CFH))[i]=h; ((u16*)(wsb+CFL))[i]=l;
    } else if (i < 24576){
        int j2=i-16384;
        int e=j2&7, lane=(j2>>3)&63, g=j2>>9;
        int mt=g&7, ks=g>>3;
        int f = mt*16+(lane&15), c = ks*32+((lane>>4)<<3)+e;
        float v = fc1w[f*64+c];
        u16 h,l; bsplit(v,h,l);
        ((u16*)(wsb+F1H))[j2]=h; ((u16*)(wsb+F1L))[j2]=l;
    }
}

// ================= fc0 =================
__global__ __launch_bounds__(256) void k_fc0(const float* __restrict__ x,
    const float* __restrict__ w, const float* __restrict__ b,
    u16* __restrict__ vh, u16* __restrict__ vl){
    __shared__ float xs[1024*3];
    __shared__ float ws3[192], bs[64];
    int t = threadIdx.x;
    size_t pb = (size_t)blockIdx.x*1024;
    const float4* xg = (const float4*)(x + pb*3);
    float4* xs4 = (float4*)xs;
    #pragma unroll
    for (int k=0;k<3;k++) xs4[t + k*256] = xg[t + k*256];
    if (t<192) ws3[t]=w[t];
    if (t<64) bs[t]=b[t];
    __syncthreads();
    int p0 = t*4;
    float X0[4],X1[4],X2[4];
    #pragma unroll
    for(int e=0;e<4;e++){X0[e]=xs[(p0+e)*3];X1[e]=xs[(p0+e)*3+1];X2[e]=xs[(p0+e)*3+2];}
    for (int c=0;c<64;c++){
        float w0=ws3[c*3],w1=ws3[c*3+1],w2=ws3[c*3+2],bc=bs[c];
        us4 sh, sl;
        #pragma unroll
        for(int e=0;e<4;e++){
            float v = w0*X0[e]+w1*X1[e]+w2*X2[e]+bc;
            u16 hh,ll; bsplit(v,hh,ll); sh[e]=hh; sl[e]=ll;
        }
        *(us4*)(vh + (size_t)c*NP + pb + p0) = sh;
        *(us4*)(vl + (size_t)c*NP + pb + p0) = sl;
    }
}

// ================= F1: XW_T[j][c][h] (split bf16) =================
__global__ __launch_bounds__(256) void k_f1(const u16* __restrict__ vh, const u16* __restrict__ vl,
    const u16* __restrict__ twh, const u16* __restrict__ twl,
    u16* __restrict__ xwh, u16* __restrict__ xwl){
    int lane = threadIdx.x & 63, wv = threadIdx.x >> 6;
    int rowa = blockIdx.x*64 + wv*16 + (lane&15);
    const u16* ah = vh + (size_t)rowa*512 + ((lane>>4)<<3);
    const u16* al = vl + (size_t)rowa*512 + ((lane>>4)<<3);
    f32x4 acc[3];
    #pragma unroll
    for (int nt = 0; nt < 3; ++nt) acc[nt] = (f32x4){0.f,0.f,0.f,0.f};
    for (int kk = 0; kk < 16; ++kk){
        bf16x8 Ah = *reinterpret_cast<const bf16x8*>(ah + kk*32);
        bf16x8 Al = *reinterpret_cast<const bf16x8*>(al + kk*32);
        #pragma unroll
        for (int nt = 0; nt < 3; ++nt){
            size_t bo = ((size_t)(kk*3+nt)*64 + lane)*8;
            bf16x8 Bh = *reinterpret_cast<const bf16x8*>(twh + bo);
            bf16x8 Bl = *reinterpret_cast<const bf16x8*>(twl + bo);
            acc[nt] = MFMA16(Ah, Bh, acc[nt], 0,0,0);
            acc[nt] = MFMA16(Ah, Bl, acc[nt], 0,0,0);
            acc[nt] = MFMA16(Al, Bh, acc[nt], 0,0,0);
        }
    }
    int r0 = blockIdx.x*64 + wv*16 + ((lane>>4)<<2);
    int c = r0>>9, h0 = r0&511;
    int colj = lane&15;
    #pragma unroll
    for (int nt = 0; nt < 3; ++nt){
        int j = nt*16 + colj;
        us4 uh, ul;
        #pragma unroll
        for (int rg = 0; rg < 4; ++rg){
            u16 hh,ll; bsplit(acc[nt][rg],hh,ll); uh[rg]=hh; ul[rg]=ll;
        }
        size_t off = ((size_t)j*64 + c)*512 + h0;
        *(us4*)(xwh + off) = uh;
        *(us4*)(xwl + off) = ul;
    }
}

// ================= F2: MFMA over h, K-split in 2 =================
__global__ __launch_bounds__(256) void k_f2(const char* __restrict__ wsb, float* __restrict__ xfP){
    int b = blockIdx.x; int kx = b>>1, kh = b&1;
    int lane = threadIdx.x&63, wv = threadIdx.x>>6;
    const u16* thch=(const u16*)(wsb+THC2H); const u16* thcl=(const u16*)(wsb+THC2L);
    const u16* thsh=(const u16*)(wsb+THS2H); const u16* thsl=(const u16*)(wsb+THS2L);
    const u16* xwh=(const u16*)(wsb+XWH);   const u16* xwl=(const u16*)(wsb+XWL);
    f32x4 aA[3],aB[3],aC[3],aD[3];
    #pragma unroll
    for(int mt=0;mt<3;mt++){aA[mt]=(f32x4){0,0,0,0};aB[mt]=aA[mt];aC[mt]=aA[mt];aD[mt]=aA[mt];}
    int g8 = (lane>>4)<<3;
    int mrow = lane&15;
    int cB = wv*16 + (lane&15);
    size_t bre = ((size_t)(2*kx)*64 + cB)*512;
    size_t bim = ((size_t)(2*kx+1)*64 + cB)*512;
    for (int kk = kh*8; kk < kh*8+8; ++kk){
        int hof = kk*32 + g8;
        bf16x8 XRh = *reinterpret_cast<const bf16x8*>(xwh + bre + hof);
        bf16x8 XRl = *reinterpret_cast<const bf16x8*>(xwl + bre + hof);
        bf16x8 XIh = *reinterpret_cast<const bf16x8*>(xwh + bim + hof);
        bf16x8 XIl = *reinterpret_cast<const bf16x8*>(xwl + bim + hof);
        #pragma unroll
        for (int mt=0;mt<3;mt++){
            size_t ao = (size_t)(mt*16+mrow)*512 + hof;
            bf16x8 Ch = *reinterpret_cast<const bf16x8*>(thch+ao);
            bf16x8 Cl = *reinterpret_cast<const bf16x8*>(thcl+ao);
            bf16x8 Sh = *reinterpret_cast<const bf16x8*>(thsh+ao);
            bf16x8 Sl = *reinterpret_cast<const bf16x8*>(thsl+ao);
            aA[mt]=MFMA16(Ch,XRh,aA[mt],0,0,0); aA[mt]=MFMA16(Ch,XRl,aA[mt],0,0,0); aA[mt]=MFMA16(Cl,XRh,aA[mt],0,0,0);
            aB[mt]=MFMA16(Sh,XIh,aB[mt],0,0,0); aB[mt]=MFMA16(Sh,XIl,aB[mt],0,0,0); aB[mt]=MFMA16(Sl,XIh,aB[mt],0,0,0);
            aC[mt]=MFMA16(Ch,XIh,aC[mt],0,0,0); aC[mt]=MFMA16(Ch,XIl,aC[mt],0,0,0); aC[mt]=MFMA16(Cl,XIh,aC[mt],0,0,0);
            aD[mt]=MFMA16(Sh,XRh,aD[mt],0,0,0); aD[mt]=MFMA16(Sh,XRl,aD[mt],0,0,0); aD[mt]=MFMA16(Sl,XRh,aD[mt],0,0,0);
        }
    }
    #pragma unroll
    for (int mt=0;mt<3;mt++)
        #pragma unroll
        for (int rg=0;rg<4;rg++){
            int m = mt*16 + ((lane>>4)<<2) + rg;
            if (m < 40){
                float re = aA[mt][rg]+aB[mt][rg];
                float im = aC[mt][rg]-aD[mt][rg];
                size_t xo = ((size_t)kh*64 + cB)*1600 + (size_t)(m*20+kx)*2;
                xfP[xo] = re; xfP[xo+1] = im;
            }
        }
}

// ================= MIX: coalesced, i-split in 2 =================
__global__ __launch_bounds__(256) void k_mix(const float* __restrict__ w1r,const float* __restrict__ w1i,
    const float* __restrict__ w2r,const float* __restrict__ w2i,
    const float* __restrict__ xfP, float* __restrict__ ypart){
    __shared__ float xs[2][800];
    int b = blockIdx.x;
    int iseg = b>>7, half = (b>>6)&1, o = b&63;
    int t = threadIdx.x;
    const float* wr = (half? w2r : w1r) + o*400;
    const float* wi = (half? w2i : w1i) + o*400;
    const float* xp0 = xfP + half*800;
    const float* xp1 = xfP + (size_t)64*1600 + half*800;
    int i0 = iseg*32;
    {
        const float* a = xp0 + (size_t)i0*1600; const float* c = xp1 + (size_t)i0*1600;
        xs[0][t]=a[t]+c[t]; xs[0][t+256]=a[t+256]+c[t+256];
        if (t<288) xs[0][t+512]=a[t+512]+c[t+512];
    }
    int p1 = t, p2 = t+256; bool has2 = (p2<400);
    float ar1=0,ai1=0,ar2=0,ai2=0;
    size_t wof = (size_t)i0*25600;
    float wAr1=wr[wof+p1], wAi1=wi[wof+p1];
    float wAr2=0,wAi2=0;
    if(has2){ wAr2=wr[wof+p2]; wAi2=wi[wof+p2]; }
    __syncthreads();
    for (int ii=0; ii<32; ++ii){
        int cur = ii&1;
        if (ii<31){
            int i = i0+ii+1;
            const float* a = xp0 + (size_t)i*1600; const float* c = xp1 + (size_t)i*1600;
            float* d = xs[cur^1];
            d[t]=a[t]+c[t]; d[t+256]=a[t+256]+c[t+256];
            if(t<288) d[t+512]=a[t+512]+c[t+512];
        }
        float wBr1=0,wBi1=0,wBr2=0,wBi2=0;
        if (ii<31){
            size_t wo2 = (size_t)(i0+ii+1)*25600;
            wBr1=wr[wo2+p1]; wBi1=wi[wo2+p1];
            if(has2){ wBr2=wr[wo2+p2]; wBi2=wi[wo2+p2]; }
        }
        float xr=xs[cur][2*p1], xi=xs[cur][2*p1+1];
        ar1 += xr*wAr1 - xi*wAi1; ai1 += xr*wAi1 + xi*wAr1;
        if (has2){
            float xr2=xs[cur][2*p2], xi2=xs[cur][2*p2+1];
            ar2 += xr2*wAr2 - xi2*wAi2; ai2 += xr2*wAi2 + xi2*wAr2;
        }
        wAr1=wBr1; wAi1=wBi1; wAr2=wBr2; wAi2=wBi2;
        __syncthreads();
    }
    int mode1 = half*400 + p1;
    size_t y1 = ((size_t)(iseg*800 + mode1)*64 + o)*2;
    ypart[y1]=ar1; ypart[y1+1]=ai1;
    if (has2){
        int mode2 = half*400 + p2;
        size_t y2 = ((size_t)(iseg*800 + mode2)*64 + o)*2;
        ypart[y2]=ar2; ypart[y2+1]=ai2;
    }
}

// ================= MIXRED: sum partials, scale, split, frag layout =================
__global__ void k_mixred(const float* __restrict__ ypart, char* wsb){
    int g = blockIdx.x*256+threadIdx.x;   // 81920
    int m = g&63, o=(g>>6)&63, kx=g>>12;
    float vr=0.f, vi=0.f;
    if (m<40){
        int mode = m*20+kx;
        size_t i0 = ((size_t)mode*64+o)*2;
        size_t i1 = ((size_t)(800+mode)*64+o)*2;
        float sc = (kx==0?1.f:2.f)*(1.f/262144.f);
        vr = (ypart[i0]+ypart[i1])*sc;
        vi = (ypart[i0+1]+ypart[i1+1])*sc;
    }
    u16 h,l; size_t yo = ((size_t)kx*64+o)*64+m;
    bsplit(vr,h,l); ((u16*)(wsb+YRH))[yo]=h; ((u16*)(wsb+YRL))[yo]=l;
    bsplit(vi,h,l); ((u16*)(wsb+YIH))[yo]=h; ((u16*)(wsb+YIL))[yo]=l;
}

// ================= I1: MFMA inverse-H DFT -> Z frags =================
__global__ __launch_bounds__(256) void k_i1(const char* __restrict__ wsb,
    u16* __restrict__ zh, u16* __restrict__ zl){
    int b = blockIdx.x; int kx = b>>3, hb = b&7;
    int lane = threadIdx.x&63, wv = threadIdx.x>>6;
    const u16* thcAh=(const u16*)(wsb+THCAH); const u16* thcAl=(const u16*)(wsb+THCAL);
    const u16* thsAh=(const u16*)(wsb+THSAH); const u16* thsAl=(const u16*)(wsb+THSAL);
    const u16* thsnh=(const u16*)(wsb+THSNH); const u16* thsnl=(const u16*)(wsb+THSNL);
    const u16* yrh=(const u16*)(wsb+YRH); const u16* yrl=(const u16*)(wsb+YRL);
    const u16* yih=(const u16*)(wsb+YIH); const u16* yil=(const u16*)(wsb+YIL);
    f32x4 aR[4], aI[4];
    #pragma unroll
    for(int nt=0;nt<4;nt++){aR[nt]=(f32x4){0,0,0,0}; aI[nt]=aR[nt];}
    int g8 = (lane>>4)<<3;
    int hrow = hb*64 + wv*16 + (lane&15);
    #pragma unroll
    for (int ks=0; ks<2; ++ks){
        size_t ao = (size_t)hrow*64 + ks*32 + g8;
        bf16x8 Ch=*reinterpret_cast<const bf16x8*>(thcAh+ao);
        bf16x8 Cl=*reinterpret_cast<const bf16x8*>(thcAl+ao);
        bf16x8 Sh=*reinterpret_cast<const bf16x8*>(thsAh+ao);
        bf16x8 Sl=*reinterpret_cast<const bf16x8*>(thsAl+ao);
        bf16x8 Nh=*reinterpret_cast<const bf16x8*>(thsnh+ao);
        bf16x8 Nl=*reinterpret_cast<const bf16x8*>(thsnl+ao);
        #pragma unroll
        for (int nt=0; nt<4; ++nt){
            int o = nt*16+(lane&15);
            size_t bo = ((size_t)kx*64+o)*64 + ks*32 + g8;
            bf16x8 Rh=*reinterpret_cast<const bf16x8*>(yrh+bo);
            bf16x8 Rl=*reinterpret_cast<const bf16x8*>(yrl+bo);
            bf16x8 Ih=*reinterpret_cast<const bf16x8*>(yih+bo);
            bf16x8 Il=*reinterpret_cast<const bf16x8*>(yil+bo);
            aR[nt]=MFMA16(Ch,Rh,aR[nt],0,0,0); aR[nt]=MFMA16(Ch,Rl,aR[nt],0,0,0); aR[nt]=MFMA16(Cl,Rh,aR[nt],0,0,0);
            aR[nt]=MFMA16(Nh,Ih,aR[nt],0,0,0); aR[nt]=MFMA16(Nh,Il,aR[nt],0,0,0); aR[nt]=MFMA16(Nl,Ih,aR[nt],0,0,0);
            aI[nt]=MFMA16(Sh,Rh,aI[nt],0,0,0); aI[nt]=MFMA16(Sh,Rl,aI[nt],0,0,0); aI[nt]=MFMA16(Sl,Rh,aI[nt],0,0,0);
            aI[nt]=MFMA16(Ch,Ih,aI[nt],0,0,0); aI[nt]=MFMA16(Ch,Il,aI[nt],0,0,0); aI[nt]=MFMA16(Cl,Ih,aI[nt],0,0,0);
        }
    }
    #pragma unroll
    for (int nt=0;nt<4;nt++)
        #pragma unroll
        for (int rg=0;rg<4;rg++){
            int h = hb*64 + wv*16 + ((lane>>4)<<2) + rg;
            int o = nt*16+(lane&15);
            size_t za = ((size_t)h*64+o)*64 + 2*kx;
            u16 h1,l1,h2,l2;
            bsplit(aR[nt][rg],h1,l1); bsplit(aI[nt][rg],h2,l2);
            us2 sh={h1,h2}, sl={l1,l2};
            *(us2*)(zh+za)=sh; *(us2*)(zl+za)=sl;
        }
}

// ================= SCT: conv + spectral + tanh =================
#define SWZ(c,p) ((c) ^ (((p)&7)<<3))
__global__ __launch_bounds__(256) void k_sct(u16* __restrict__ vh, u16* __restrict__ vl,
    const char* __restrict__ wsb, int L, const float* __restrict__ cb,
    const u16* __restrict__ zh, const u16* __restrict__ zl){
    __shared__ u16 sh_[4096];
    __shared__ u16 sl_[4096];
    int t = threadIdx.x, lane = t&63, wv = t>>6;
    int h = blockIdx.x>>3, pb = (blockIdx.x&7)<<6;
    size_t gbase = (size_t)h*512 + pb;
    {
        int c = t>>2, p0=(t&3)<<4;
        short8 a0 = *(const short8*)(vh + (size_t)c*NP + gbase + p0);
        short8 a1 = *(const short8*)(vh + (size_t)c*NP + gbase + p0+8);
        short8 b0 = *(const short8*)(vl + (size_t)c*NP + gbase + p0);
        short8 b1 = *(const short8*)(vl + (size_t)c*NP + gbase + p0+8);
        #pragma unroll
        for (int e=0;e<8;e++){
            sh_[(p0+e)*64 + SWZ(c,p0+e)] = (u16)a0[e];
            sh_[(p0+8+e)*64 + SWZ(c,p0+8+e)] = (u16)a1[e];
            sl_[(p0+e)*64 + SWZ(c,p0+e)] = (u16)b0[e];
            sl_[(p0+8+e)*64 + SWZ(c,p0+8+e)] = (u16)b1[e];
        }
    }
    __syncthreads();
    f32x4 acc[4];
    #pragma unroll
    for (int mt=0;mt<4;mt++) acc[mt]=(f32x4){0,0,0,0};
    int colp = wv*16 + (lane&15);
    int g = lane>>4;
    const u16* cfh=(const u16*)(wsb+CFH); const u16* cfl=(const u16*)(wsb+CFL);
    const u16* t2h=(const u16*)(wsb+T2H); const u16* t2l=(const u16*)(wsb+T2L);
    #pragma unroll
    for (int ks=0;ks<2;ks++){
        int o8 = ks*4+g;
        int so = colp*64 + ((o8 ^ (colp&7))<<3);
        bf16x8 Bh = *reinterpret_cast<const bf16x8*>(sh_+so);
        bf16x8 Bl = *reinterpret_cast<const bf16x8*>(sl_+so);
        #pragma unroll
        for (int mt=0;mt<4;mt++){
            size_t fo = (size_t)(((L*2+ks)*4+mt)*64 + lane)*8;
            bf16x8 Ah = *reinterpret_cast<const bf16x8*>(cfh+fo);
            bf16x8 Al = *reinterpret_cast<const bf16x8*>(cfl+fo);
            acc[mt]=MFMA16(Ah,Bh,acc[mt],0,0,0);
            acc[mt]=MFMA16(Ah,Bl,acc[mt],0,0,0);
            acc[mt]=MFMA16(Al,Bh,acc[mt],0,0,0);
        }
    }
    int wt = (pb>>4) + wv;
    #pragma unroll
    for (int ks=0;ks<2;ks++){
        size_t bo = ((size_t)(wt*2+ks)*64 + lane)*8;
        bf16x8 Bh = *reinterpret_cast<const bf16x8*>(t2h+bo);
        bf16x8 Bl = *reinterpret_cast<const bf16x8*>(t2l+bo);
        #pragma unroll
        for (int mt=0;mt<4;mt++){
            size_t ao = (((size_t)h*64 + mt*16+(lane&15))*64) + ks*32 + (g<<3);
            bf16x8 Ah = *reinterpret_cast<const bf16x8*>(zh+ao);
            bf16x8 Al = *reinterpret_cast<const bf16x8*>(zl+ao);
            acc[mt]=MFMA16(Ah,Bh,acc[mt],0,0,0);
            acc[mt]=MFMA16(Ah,Bl,acc[mt],0,0,0);
            acc[mt]=MFMA16(Al,Bh,acc[mt],0,0,0);
        }
    }
    size_t pg = gbase + colp;
    #pragma unroll
    for (int mt=0;mt<4;mt++)
        #pragma unroll
        for (int rg=0;rg<4;rg++){
            int o = mt*16 + (g<<2) + rg;
            float val = tanhfast(acc[mt][rg] + cb[o]);
            u16 hh,ll; bsplit(val,hh,ll);
            vh[(size_t)o*NP + pg]=hh; vl[(size_t)o*NP + pg]=ll;
        }
}

// ================= FC1+FC2 =================
__global__ __launch_bounds__(256) void k_fc12(const u16* __restrict__ vh, const u16* __restrict__ vl,
    const char* __restrict__ wsb, const float* __restrict__ b1,
    const float* __restrict__ w2, const float* __restrict__ b2, float* __restrict__ out){
    __shared__ u16 sh_[4096];
    __shared__ u16 sl_[4096];
    int t = threadIdx.x, lane = t&63, wv = t>>6;
    size_t pb = (size_t)blockIdx.x*64;
    {
        int c = t>>2, p0=(t&3)<<4;
        short8 a0 = *(const short8*)(vh + (size_t)c*NP + pb + p0);
        short8 a1 = *(const short8*)(vh + (size_t)c*NP + pb + p0+8);
        short8 b0 = *(const short8*)(vl + (size_t)c*NP + pb + p0);
        short8 b1 = *(const short8*)(vl + (size_t)c*NP + pb + p0+8);
        #pragma unroll
        for (int e=0;e<8;e++){
            sh_[(p0+e)*64 + SWZ(c,p0+e)] = (u16)a0[e];
            sh_[(p0+8+e)*64 + SWZ(c,p0+8+e)] = (u16)a1[e];
            sl_[(p0+e)*64 + SWZ(c,p0+e)] = (u16)b0[e];
            sl_[(p0+8+e)*64 + SWZ(c,p0+8+e)] = (u16)b1[e];
        }
    }
    __syncthreads();
    f32x4 acc[8];
    #pragma unroll
    for (int mt=0;mt<8;mt++) acc[mt]=(f32x4){0,0,0,0};
    int colp = wv*16 + (lane&15);
    int g = lane>>4;
    const u16* f1h=(const u16*)(wsb+F1H); const u16* f1l=(const u16*)(wsb+F1L);
    #pragma unroll
    for (int ks=0;ks<2;ks++){
        int o8 = ks*4+g;
        int so = colp*64 + ((o8 ^ (colp&7))<<3);
        bf16x8 Bh = *reinterpret_cast<const bf16x8*>(sh_+so);
        bf16x8 Bl = *reinterpret_cast<const bf16x8*>(sl_+so);
        #pragma unroll
        for (int mt=0;mt<8;mt++){
            size_t fo = (size_t)((ks*8+mt)*64 + lane)*8;
            bf16x8 Ah = *reinterpret_cast<const bf16x8*>(f1h+fo);
            bf16x8 Al = *reinterpret_cast<const bf16x8*>(f1l+fo);
            acc[mt]=MFMA16(Ah,Bh,acc[mt],0,0,0);
            acc[mt]=MFMA16(Ah,Bl,acc[mt],0,0,0);
            acc[mt]=MFMA16(Al,Bh,acc[mt],0,0,0);
        }
    }
    float s = 0.f;
    #pragma unroll
    for (int mt=0;mt<8;mt++)
        #pragma unroll
        for (int rg=0;rg<4;rg++){
            int f = mt*16 + (g<<2) + rg;
            s += w2[f] * tanhfast(acc[mt][rg] + b1[f]);
        }
    s += __shfl_xor(s, 16);
    s += __shfl_xor(s, 32);
    if (lane < 16) out[pb + wv*16 + lane] = s + b2[0];
}

extern "C" void kernel_launch(void* const* d_in, const int* in_sizes, int n_in,
                              void* d_out, int out_size, void* d_ws, size_t ws_size,
                              hipStream_t stream) {
    const float* x     = (const float*)d_in[0];
    const float* fc0w  = (const float*)d_in[1];
    const float* fc0b  = (const float*)d_in[2];
    const float* sw1r  = (const float*)d_in[3];
    const float* sw1i  = (const float*)d_in[4];
    const float* sw2r  = (const float*)d_in[5];
    const float* sw2i  = (const float*)d_in[6];
    const float* convw = (const float*)d_in[7];
    const float* convb = (const float*)d_in[8];
    const float* fc1w  = (const float*)d_in[9];
    const float* fc1b  = (const float*)d_in[10];
    const float* fc2w  = (const float*)d_in[11];
    const float* fc2b  = (const float*)d_in[12];
    char* wsb = (char*)d_ws;
    float* out = (float*)d_out;

    u16* twh = (u16*)(wsb+TWH); u16* twl = (u16*)(wsb+TWL);
    u16* xwh = (u16*)(wsb+XWH); u16* xwl = (u16*)(wsb+XWL);
    float* xfP = (float*)(wsb+XFP);
    float* ypart = (float*)(wsb+YPART);
    u16* zh = (u16*)(wsb+ZH); u16* zl = (u16*)(wsb+ZL);
    u16* vh = (u16*)(wsb+VH); u16* vl = (u16*)(wsb+VL);

    k_tables<<<448, 256, 0, stream>>>(wsb);
    k_wprep<<<96, 256, 0, stream>>>(convw, fc1w, wsb);
    k_fc0<<<256, 256, 0, stream>>>(x, fc0w, fc0b, vh, vl);
    for (int L = 0; L < 4; ++L){
        size_t so = (size_t)L * 64 * 64 * 400;
        k_f1<<<512, 256, 0, stream>>>(vh, vl, twh, twl, xwh, xwl);
        k_f2<<<40, 256, 0, stream>>>(wsb, xfP);
        k_mix<<<256, 256, 0, stream>>>(sw1r+so, sw1i+so, sw2r+so, sw2i+so, xfP, ypart);
        k_mixred<<<320, 256, 0, stream>>>(ypart, wsb);
        k_i1<<<160, 256, 0, stream>>>(wsb, zh, zl);
        k_sct<<<4096, 256, 0, stream>>>(vh, vl, wsb, L, convb + (size_t)L*64, zh, zl);
    }
    k_fc12<<<4096, 256, 0, stream>>>(vh, vl, wsb, fc1b, fc2w, fc2b, out);
}

// Round 6
// 729.365 us; speedup vs baseline: 4.4065x; 1.1053x over previous
//
#include <hip/hip_runtime.h>
#include <math.h>

typedef unsigned short u16;
typedef __attribute__((ext_vector_type(8))) short short8;
typedef __attribute__((ext_vector_type(8))) short bf16x8;
typedef __attribute__((ext_vector_type(4))) unsigned short us4;
typedef __attribute__((ext_vector_type(2))) unsigned short us2;
typedef __attribute__((ext_vector_type(8))) unsigned short us8;
typedef __attribute__((ext_vector_type(4))) float f32x4;

#define NP (512*512)
#define MFMA16 __builtin_amdgcn_mfma_f32_16x16x32_bf16

// ---- workspace byte offsets (all 256-aligned) ----
#define TWH   0u
#define TWL   49152u
#define T2H   98304u
#define T2L   163840u
#define THC2H 229376u
#define THC2L 278528u
#define THS2H 327680u
#define THS2L 376832u
#define THCAH 425984u
#define THCAL 491520u
#define THSAH 557056u
#define THSAL 622592u
#define THSNH 688128u
#define THSNL 753664u
#define CFH   819200u
#define CFL   851968u
#define F1H   884736u
#define F1L   901120u
#define XWH   917504u
#define XWL   4063232u
#define XFP   7208960u
#define YPART 8028160u
#define YRH   8847360u
#define YRL   9011200u
#define YIH   9175040u
#define YIL   9338880u
#define ZH    9502720u
#define ZL    13697024u
#define VH    17891328u
#define VL    51445760u

__device__ __forceinline__ u16 brnd(float x){
    unsigned u = __float_as_uint(x);
    unsigned r = (u + 0x7FFFu + ((u>>16)&1u)) >> 16;
    return (u16)r;
}
__device__ __forceinline__ float fbf(u16 h){ return __uint_as_float(((unsigned)h)<<16); }
__device__ __forceinline__ void bsplit(float x, u16& h, u16& l){
    h = brnd(x); l = brnd(x - fbf(h));
}
__device__ __forceinline__ float tanhfast(float x){
    x = fminf(10.f, fmaxf(-10.f, x));
    float e = __expf(2.f*x);
    return (e-1.f)/(e+1.f);
}

// ================= setup: tables + weight frags =================
__global__ void k_setup(char* wsb, const float* __restrict__ convw, const float* __restrict__ fc1w){
    int i = blockIdx.x*256 + threadIdx.x;
    const float c2pi = 6.283185307179586f/512.0f;
    if (i < 24576){                         // TW
        int e=i&7, lane=(i>>3)&63, g=i>>9; int nt=g%3;
        int k = (g/3)*32 + ((lane>>4)<<3) + e;
        int n = nt*16 + (lane&15);
        float v=0.f;
        if(n<40){int kx=n>>1; float a=c2pi*(float)((kx*k)&511); v=(n&1)?-sinf(a):cosf(a);}
        u16 h,l; bsplit(v,h,l);
        ((u16*)(wsb+TWH))[i]=h; ((u16*)(wsb+TWL))[i]=l;
    } else if (i < 57344){                  // T2
        int j2=i-24576;
        int e=j2&7, lane=(j2>>3)&63, g=j2>>9; int ks=g&1, wt=g>>1;
        int j = ks*32 + ((lane>>4)<<3) + e;
        int w = wt*16 + (lane&15);
        float v=0.f;
        if(j<40){int kx=j>>1; float a=c2pi*(float)((kx*w)&511); v=(j&1)?-sinf(a):cosf(a);}
        u16 h,l; bsplit(v,h,l);
        ((u16*)(wsb+T2H))[j2]=h; ((u16*)(wsb+T2L))[j2]=l;
    } else if (i < 81920){                  // f2 A [m48][h512]
        int j2 = i-57344;
        int m=j2>>9, hh=j2&511;
        float vc=0.f,vs=0.f;
        if(m<40){int ky=(m<20)?m:(472+m); float a=c2pi*(float)((ky*hh)&511); vc=cosf(a); vs=sinf(a);}
        u16 h,l;
        bsplit(vc,h,l); ((u16*)(wsb+THC2H))[j2]=h; ((u16*)(wsb+THC2L))[j2]=l;
        bsplit(vs,h,l); ((u16*)(wsb+THS2H))[j2]=h; ((u16*)(wsb+THS2L))[j2]=l;
    } else if (i < 114688){                 // i1 A [h512][m64]
        int j2 = i-81920;
        int hh=j2>>6, m=j2&63;
        float vc=0.f,vs=0.f;
        if(m<40){int ky=(m<20)?m:(472+m); float a=c2pi*(float)((ky*hh)&511); vc=cosf(a); vs=sinf(a);}
        u16 h,l;
        bsplit(vc,h,l);  ((u16*)(wsb+THCAH))[j2]=h; ((u16*)(wsb+THCAL))[j2]=l;
        bsplit(vs,h,l);  ((u16*)(wsb+THSAH))[j2]=h; ((u16*)(wsb+THSAL))[j2]=l;
        bsplit(-vs,h,l); ((u16*)(wsb+THSNH))[j2]=h; ((u16*)(wsb+THSNL))[j2]=l;
    } else {                                // weight frags
        int j = i - 114688;
        if (j < 16384){
            int e=j&7, lane=(j>>3)&63, g=j>>9;
            int mt=g&3, ks=(g>>2)&1, L=g>>3;
            int o = mt*16+(lane&15), c = ks*32+((lane>>4)<<3)+e;
            float v = convw[L*4096 + o*64 + c];
            u16 h,l; bsplit(v,h,l);
            ((u16*)(wsb+CFH))[j]=h; ((u16*)(wsb+CFL))[j]=l;
        } else {
            int j2=j-16384;
            int e=j2&7, lane=(j2>>3)&63, g=j2>>9;
            int mt=g&7, ks=g>>3;
            int f = mt*16+(lane&15), c = ks*32+((lane>>4)<<3)+e;
            float v = fc1w[f*64+c];
            u16 h,l; bsplit(v,h,l);
            ((u16*)(wsb+F1H))[j2]=h; ((u16*)(wsb+F1L))[j2]=l;
        }
    }
}

// ================= fc0 =================
__global__ __launch_bounds__(256) void k_fc0(const float* __restrict__ x,
    const float* __restrict__ w, const float* __restrict__ b,
    u16* __restrict__ vh, u16* __restrict__ vl){
    __shared__ float xs[1024*3];
    __shared__ float ws3[192], bs[64];
    int t = threadIdx.x;
    size_t pb = (size_t)blockIdx.x*1024;
    const float4* xg = (const float4*)(x + pb*3);
    float4* xs4 = (float4*)xs;
    #pragma unroll
    for (int k=0;k<3;k++) xs4[t + k*256] = xg[t + k*256];
    if (t<192) ws3[t]=w[t];
    if (t<64) bs[t]=b[t];
    __syncthreads();
    int p0 = t*4;
    float X0[4],X1[4],X2[4];
    #pragma unroll
    for(int e=0;e<4;e++){X0[e]=xs[(p0+e)*3];X1[e]=xs[(p0+e)*3+1];X2[e]=xs[(p0+e)*3+2];}
    for (int c=0;c<64;c++){
        float w0=ws3[c*3],w1=ws3[c*3+1],w2=ws3[c*3+2],bc=bs[c];
        us4 sh, sl;
        #pragma unroll
        for(int e=0;e<4;e++){
            float v = w0*X0[e]+w1*X1[e]+w2*X2[e]+bc;
            u16 hh,ll; bsplit(v,hh,ll); sh[e]=hh; sl[e]=ll;
        }
        *(us4*)(vh + (size_t)c*NP + pb + p0) = sh;
        *(us4*)(vl + (size_t)c*NP + pb + p0) = sl;
    }
}

// ================= F1 =================
__global__ __launch_bounds__(256) void k_f1(const u16* __restrict__ vh, const u16* __restrict__ vl,
    const u16* __restrict__ twh, const u16* __restrict__ twl,
    u16* __restrict__ xwh, u16* __restrict__ xwl){
    int lane = threadIdx.x & 63, wv = threadIdx.x >> 6;
    int rowa = blockIdx.x*64 + wv*16 + (lane&15);
    const u16* ah = vh + (size_t)rowa*512 + ((lane>>4)<<3);
    const u16* al = vl + (size_t)rowa*512 + ((lane>>4)<<3);
    f32x4 acc[3];
    #pragma unroll
    for (int nt = 0; nt < 3; ++nt) acc[nt] = (f32x4){0.f,0.f,0.f,0.f};
    #pragma unroll 2
    for (int kk = 0; kk < 16; ++kk){
        bf16x8 Ah = *reinterpret_cast<const bf16x8*>(ah + kk*32);
        bf16x8 Al = *reinterpret_cast<const bf16x8*>(al + kk*32);
        bf16x8 Bh[3], Bl[3];
        #pragma unroll
        for (int nt = 0; nt < 3; ++nt){
            size_t bo = ((size_t)(kk*3+nt)*64 + lane)*8;
            Bh[nt] = *reinterpret_cast<const bf16x8*>(twh + bo);
            Bl[nt] = *reinterpret_cast<const bf16x8*>(twl + bo);
        }
        #pragma unroll
        for (int nt = 0; nt < 3; ++nt){
            acc[nt] = MFMA16(Ah, Bh[nt], acc[nt], 0,0,0);
            acc[nt] = MFMA16(Ah, Bl[nt], acc[nt], 0,0,0);
            acc[nt] = MFMA16(Al, Bh[nt], acc[nt], 0,0,0);
        }
    }
    int r0 = blockIdx.x*64 + wv*16 + ((lane>>4)<<2);
    int c = r0>>9, h0 = r0&511;
    int colj = lane&15;
    #pragma unroll
    for (int nt = 0; nt < 3; ++nt){
        int j = nt*16 + colj;
        us4 uh, ul;
        #pragma unroll
        for (int rg = 0; rg < 4; ++rg){
            u16 hh,ll; bsplit(acc[nt][rg],hh,ll); uh[rg]=hh; ul[rg]=ll;
        }
        size_t off = ((size_t)j*64 + c)*512 + h0;
        *(us4*)(xwh + off) = uh;
        *(us4*)(xwl + off) = ul;
    }
}

// ================= F2: one mt per block =================
__global__ __launch_bounds__(256) void k_f2(const char* __restrict__ wsb, float* __restrict__ xfP){
    int b = blockIdx.x;             // 120 = kx*6 + mt*2 + kh
    int kx = b/6, r = b%6, mt = r>>1, kh = r&1;
    int lane = threadIdx.x&63, wv = threadIdx.x>>6;
    const u16* thch=(const u16*)(wsb+THC2H); const u16* thcl=(const u16*)(wsb+THC2L);
    const u16* thsh=(const u16*)(wsb+THS2H); const u16* thsl=(const u16*)(wsb+THS2L);
    const u16* xwh=(const u16*)(wsb+XWH);   const u16* xwl=(const u16*)(wsb+XWL);
    f32x4 aA=(f32x4){0,0,0,0}, aB=aA, aC=aA, aD=aA;
    int g8 = (lane>>4)<<3;
    int mrow = lane&15;
    int cB = wv*16 + (lane&15);
    size_t bre = ((size_t)(2*kx)*64 + cB)*512;
    size_t bim = ((size_t)(2*kx+1)*64 + cB)*512;
    for (int kk = kh*8; kk < kh*8+8; ++kk){
        int hof = kk*32 + g8;
        bf16x8 XRh = *reinterpret_cast<const bf16x8*>(xwh + bre + hof);
        bf16x8 XRl = *reinterpret_cast<const bf16x8*>(xwl + bre + hof);
        bf16x8 XIh = *reinterpret_cast<const bf16x8*>(xwh + bim + hof);
        bf16x8 XIl = *reinterpret_cast<const bf16x8*>(xwl + bim + hof);
        size_t ao = (size_t)(mt*16+mrow)*512 + hof;
        bf16x8 Ch = *reinterpret_cast<const bf16x8*>(thch+ao);
        bf16x8 Cl = *reinterpret_cast<const bf16x8*>(thcl+ao);
        bf16x8 Sh = *reinterpret_cast<const bf16x8*>(thsh+ao);
        bf16x8 Sl = *reinterpret_cast<const bf16x8*>(thsl+ao);
        aA=MFMA16(Ch,XRh,aA,0,0,0); aA=MFMA16(Ch,XRl,aA,0,0,0); aA=MFMA16(Cl,XRh,aA,0,0,0);
        aB=MFMA16(Sh,XIh,aB,0,0,0); aB=MFMA16(Sh,XIl,aB,0,0,0); aB=MFMA16(Sl,XIh,aB,0,0,0);
        aC=MFMA16(Ch,XIh,aC,0,0,0); aC=MFMA16(Ch,XIl,aC,0,0,0); aC=MFMA16(Cl,XIh,aC,0,0,0);
        aD=MFMA16(Sh,XRh,aD,0,0,0); aD=MFMA16(Sh,XRl,aD,0,0,0); aD=MFMA16(Sl,XRh,aD,0,0,0);
    }
    #pragma unroll
    for (int rg=0;rg<4;rg++){
        int m = mt*16 + ((lane>>4)<<2) + rg;
        if (m < 40){
            float re = aA[rg]+aB[rg];
            float im = aC[rg]-aD[rg];
            size_t xo = ((size_t)kh*64 + cB)*1600 + (size_t)(m*20+kx)*2;
            xfP[xo] = re; xfP[xo+1] = im;
        }
    }
}

// ================= MIX =================
__global__ __launch_bounds__(256) void k_mix(const float* __restrict__ w1r,const float* __restrict__ w1i,
    const float* __restrict__ w2r,const float* __restrict__ w2i,
    const float* __restrict__ xfP, float* __restrict__ ypart){
    __shared__ float xs[2][800];
    int b = blockIdx.x;
    int iseg = b>>7, half = (b>>6)&1, o = b&63;
    int t = threadIdx.x;
    const float* wr = (half? w2r : w1r) + o*400;
    const float* wi = (half? w2i : w1i) + o*400;
    const float* xp0 = xfP + half*800;
    const float* xp1 = xfP + (size_t)64*1600 + half*800;
    int i0 = iseg*32;
    {
        const float* a = xp0 + (size_t)i0*1600; const float* c = xp1 + (size_t)i0*1600;
        xs[0][t]=a[t]+c[t]; xs[0][t+256]=a[t+256]+c[t+256];
        if (t<288) xs[0][t+512]=a[t+512]+c[t+512];
    }
    int p1 = t, p2 = t+256; bool has2 = (p2<400);
    float ar1=0,ai1=0,ar2=0,ai2=0;
    size_t wof = (size_t)i0*25600;
    float wAr1=wr[wof+p1], wAi1=wi[wof+p1];
    float wAr2=0,wAi2=0;
    if(has2){ wAr2=wr[wof+p2]; wAi2=wi[wof+p2]; }
    __syncthreads();
    for (int ii=0; ii<32; ++ii){
        int cur = ii&1;
        if (ii<31){
            int i = i0+ii+1;
            const float* a = xp0 + (size_t)i*1600; const float* c = xp1 + (size_t)i*1600;
            float* d = xs[cur^1];
            d[t]=a[t]+c[t]; d[t+256]=a[t+256]+c[t+256];
            if(t<288) d[t+512]=a[t+512]+c[t+512];
        }
        float wBr1=0,wBi1=0,wBr2=0,wBi2=0;
        if (ii<31){
            size_t wo2 = (size_t)(i0+ii+1)*25600;
            wBr1=wr[wo2+p1]; wBi1=wi[wo2+p1];
            if(has2){ wBr2=wr[wo2+p2]; wBi2=wi[wo2+p2]; }
        }
        float xr=xs[cur][2*p1], xi=xs[cur][2*p1+1];
        ar1 += xr*wAr1 - xi*wAi1; ai1 += xr*wAi1 + xi*wAr1;
        if (has2){
            float xr2=xs[cur][2*p2], xi2=xs[cur][2*p2+1];
            ar2 += xr2*wAr2 - xi2*wAi2; ai2 += xr2*wAi2 + xi2*wAr2;
        }
        wAr1=wBr1; wAi1=wBi1; wAr2=wBr2; wAi2=wBi2;
        __syncthreads();
    }
    int mode1 = half*400 + p1;
    size_t y1 = ((size_t)(iseg*800 + mode1)*64 + o)*2;
    ypart[y1]=ar1; ypart[y1+1]=ai1;
    if (has2){
        int mode2 = half*400 + p2;
        size_t y2 = ((size_t)(iseg*800 + mode2)*64 + o)*2;
        ypart[y2]=ar2; ypart[y2+1]=ai2;
    }
}

// ================= MIXRED =================
__global__ void k_mixred(const float* __restrict__ ypart, char* wsb){
    int g = blockIdx.x*256+threadIdx.x;
    int m = g&63, o=(g>>6)&63, kx=g>>12;
    float vr=0.f, vi=0.f;
    if (m<40){
        int mode = m*20+kx;
        size_t i0 = ((size_t)mode*64+o)*2;
        size_t i1 = ((size_t)(800+mode)*64+o)*2;
        float sc = (kx==0?1.f:2.f)*(1.f/262144.f);
        vr = (ypart[i0]+ypart[i1])*sc;
        vi = (ypart[i0+1]+ypart[i1+1])*sc;
    }
    u16 h,l; size_t yo = ((size_t)kx*64+o)*64+m;
    bsplit(vr,h,l); ((u16*)(wsb+YRH))[yo]=h; ((u16*)(wsb+YRL))[yo]=l;
    bsplit(vi,h,l); ((u16*)(wsb+YIH))[yo]=h; ((u16*)(wsb+YIL))[yo]=l;
}

// ================= I1: 128-thr blocks =================
__global__ __launch_bounds__(128) void k_i1(const char* __restrict__ wsb,
    u16* __restrict__ zh, u16* __restrict__ zl){
    int b = blockIdx.x; int kx = b>>4, hb = b&15;
    int lane = threadIdx.x&63, wv = threadIdx.x>>6;
    const u16* thcAh=(const u16*)(wsb+THCAH); const u16* thcAl=(const u16*)(wsb+THCAL);
    const u16* thsAh=(const u16*)(wsb+THSAH); const u16* thsAl=(const u16*)(wsb+THSAL);
    const u16* thsnh=(const u16*)(wsb+THSNH); const u16* thsnl=(const u16*)(wsb+THSNL);
    const u16* yrh=(const u16*)(wsb+YRH); const u16* yrl=(const u16*)(wsb+YRL);
    const u16* yih=(const u16*)(wsb+YIH); const u16* yil=(const u16*)(wsb+YIL);
    f32x4 aR[4], aI[4];
    #pragma unroll
    for(int nt=0;nt<4;nt++){aR[nt]=(f32x4){0,0,0,0}; aI[nt]=aR[nt];}
    int g8 = (lane>>4)<<3;
    int hrow = hb*32 + wv*16 + (lane&15);
    #pragma unroll
    for (int ks=0; ks<2; ++ks){
        size_t ao = (size_t)hrow*64 + ks*32 + g8;
        bf16x8 Ch=*reinterpret_cast<const bf16x8*>(thcAh+ao);
        bf16x8 Cl=*reinterpret_cast<const bf16x8*>(thcAl+ao);
        bf16x8 Sh=*reinterpret_cast<const bf16x8*>(thsAh+ao);
        bf16x8 Sl=*reinterpret_cast<const bf16x8*>(thsAl+ao);
        bf16x8 Nh=*reinterpret_cast<const bf16x8*>(thsnh+ao);
        bf16x8 Nl=*reinterpret_cast<const bf16x8*>(thsnl+ao);
        #pragma unroll
        for (int nt=0; nt<4; ++nt){
            int o = nt*16+(lane&15);
            size_t bo = ((size_t)kx*64+o)*64 + ks*32 + g8;
            bf16x8 Rh=*reinterpret_cast<const bf16x8*>(yrh+bo);
            bf16x8 Rl=*reinterpret_cast<const bf16x8*>(yrl+bo);
            bf16x8 Ih=*reinterpret_cast<const bf16x8*>(yih+bo);
            bf16x8 Il=*reinterpret_cast<const bf16x8*>(yil+bo);
            aR[nt]=MFMA16(Ch,Rh,aR[nt],0,0,0); aR[nt]=MFMA16(Ch,Rl,aR[nt],0,0,0); aR[nt]=MFMA16(Cl,Rh,aR[nt],0,0,0);
            aR[nt]=MFMA16(Nh,Ih,aR[nt],0,0,0); aR[nt]=MFMA16(Nh,Il,aR[nt],0,0,0); aR[nt]=MFMA16(Nl,Ih,aR[nt],0,0,0);
            aI[nt]=MFMA16(Sh,Rh,aI[nt],0,0,0); aI[nt]=MFMA16(Sh,Rl,aI[nt],0,0,0); aI[nt]=MFMA16(Sl,Rh,aI[nt],0,0,0);
            aI[nt]=MFMA16(Ch,Ih,aI[nt],0,0,0); aI[nt]=MFMA16(Ch,Il,aI[nt],0,0,0); aI[nt]=MFMA16(Cl,Ih,aI[nt],0,0,0);
        }
    }
    #pragma unroll
    for (int nt=0;nt<4;nt++)
        #pragma unroll
        for (int rg=0;rg<4;rg++){
            int h = hb*32 + wv*16 + ((lane>>4)<<2) + rg;
            int o = nt*16+(lane&15);
            size_t za = ((size_t)h*64+o)*64 + 2*kx;
            u16 h1,l1,h2,l2;
            bsplit(aR[nt][rg],h1,l1); bsplit(aI[nt][rg],h2,l2);
            us2 sh={h1,h2}, sl={l1,l2};
            *(us2*)(zh+za)=sh; *(us2*)(zl+za)=sl;
        }
}

// ================= SCT =================
#define SWZ(c,p) ((c) ^ (((p)&7)<<3))
__global__ __launch_bounds__(256) void k_sct(u16* __restrict__ vh, u16* __restrict__ vl,
    const char* __restrict__ wsb, int L, const float* __restrict__ cb,
    const u16* __restrict__ zh, const u16* __restrict__ zl){
    __shared__ u16 sh_[4096];
    __shared__ u16 sl_[4096];
    __shared__ unsigned so_[64*68];
    int t = threadIdx.x, lane = t&63, wv = t>>6;
    int h = blockIdx.x>>3, pb = (blockIdx.x&7)<<6;
    size_t gbase = (size_t)h*512 + pb;
    const u16* cfh=(const u16*)(wsb+CFH); const u16* cfl=(const u16*)(wsb+CFL);
    const u16* t2h=(const u16*)(wsb+T2H); const u16* t2l=(const u16*)(wsb+T2L);
    int g = lane>>4;
    int colp = wv*16 + (lane&15);
    int wt = (pb>>4) + wv;
    // ---- stage loads issue first
    int cst = t>>2, p0s=(t&3)<<4;
    short8 a0 = *(const short8*)(vh + (size_t)cst*NP + gbase + p0s);
    short8 a1 = *(const short8*)(vh + (size_t)cst*NP + gbase + p0s+8);
    short8 b0 = *(const short8*)(vl + (size_t)cst*NP + gbase + p0s);
    short8 b1 = *(const short8*)(vl + (size_t)cst*NP + gbase + p0s+8);
    // ---- ks0 frag loads in flight
    bf16x8 cA0[4][2], zA0[4][2], tB0[2];
    #pragma unroll
    for (int mt=0;mt<4;mt++){
        size_t fo = (size_t)(((L*2+0)*4+mt)*64 + lane)*8;
        cA0[mt][0] = *reinterpret_cast<const bf16x8*>(cfh+fo);
        cA0[mt][1] = *reinterpret_cast<const bf16x8*>(cfl+fo);
        size_t ao = (((size_t)h*64 + mt*16+(lane&15))*64) + (g<<3);
        zA0[mt][0] = *reinterpret_cast<const bf16x8*>(zh+ao);
        zA0[mt][1] = *reinterpret_cast<const bf16x8*>(zl+ao);
    }
    {
        size_t bo = ((size_t)(wt*2+0)*64 + lane)*8;
        tB0[0] = *reinterpret_cast<const bf16x8*>(t2h+bo);
        tB0[1] = *reinterpret_cast<const bf16x8*>(t2l+bo);
    }
    // ---- stage to LDS (swizzled transpose)
    #pragma unroll
    for (int e=0;e<8;e++){
        sh_[(p0s+e)*64 + SWZ(cst,p0s+e)] = (u16)a0[e];
        sh_[(p0s+8+e)*64 + SWZ(cst,p0s+8+e)] = (u16)a1[e];
        sl_[(p0s+e)*64 + SWZ(cst,p0s+e)] = (u16)b0[e];
        sl_[(p0s+8+e)*64 + SWZ(cst,p0s+8+e)] = (u16)b1[e];
    }
    __syncthreads();
    f32x4 acc[4];
    #pragma unroll
    for (int mt=0;mt<4;mt++) acc[mt]=(f32x4){0,0,0,0};
    // ---- ks0 conv
    {
        int so = colp*64 + ((g ^ (colp&7))<<3);
        bf16x8 Bh = *reinterpret_cast<const bf16x8*>(sh_+so);
        bf16x8 Bl = *reinterpret_cast<const bf16x8*>(sl_+so);
        #pragma unroll
        for (int mt=0;mt<4;mt++){
            acc[mt]=MFMA16(cA0[mt][0],Bh,acc[mt],0,0,0);
            acc[mt]=MFMA16(cA0[mt][0],Bl,acc[mt],0,0,0);
            acc[mt]=MFMA16(cA0[mt][1],Bh,acc[mt],0,0,0);
        }
    }
    // ---- issue ks1 loads
    bf16x8 cA1[4][2], zA1[4][2], tB1[2];
    #pragma unroll
    for (int mt=0;mt<4;mt++){
        size_t fo = (size_t)(((L*2+1)*4+mt)*64 + lane)*8;
        cA1[mt][0] = *reinterpret_cast<const bf16x8*>(cfh+fo);
        cA1[mt][1] = *reinterpret_cast<const bf16x8*>(cfl+fo);
        size_t ao = (((size_t)h*64 + mt*16+(lane&15))*64) + 32 + (g<<3);
        zA1[mt][0] = *reinterpret_cast<const bf16x8*>(zh+ao);
        zA1[mt][1] = *reinterpret_cast<const bf16x8*>(zl+ao);
    }
    {
        size_t bo = ((size_t)(wt*2+1)*64 + lane)*8;
        tB1[0] = *reinterpret_cast<const bf16x8*>(t2h+bo);
        tB1[1] = *reinterpret_cast<const bf16x8*>(t2l+bo);
    }
    // ---- ks0 spectral
    #pragma unroll
    for (int mt=0;mt<4;mt++){
        acc[mt]=MFMA16(zA0[mt][0],tB0[0],acc[mt],0,0,0);
        acc[mt]=MFMA16(zA0[mt][0],tB0[1],acc[mt],0,0,0);
        acc[mt]=MFMA16(zA0[mt][1],tB0[0],acc[mt],0,0,0);
    }
    // ---- ks1 conv
    {
        int so = colp*64 + (((4+g) ^ (colp&7))<<3);
        bf16x8 Bh = *reinterpret_cast<const bf16x8*>(sh_+so);
        bf16x8 Bl = *reinterpret_cast<const bf16x8*>(sl_+so);
        #pragma unroll
        for (int mt=0;mt<4;mt++){
            acc[mt]=MFMA16(cA1[mt][0],Bh,acc[mt],0,0,0);
            acc[mt]=MFMA16(cA1[mt][0],Bl,acc[mt],0,0,0);
            acc[mt]=MFMA16(cA1[mt][1],Bh,acc[mt],0,0,0);
        }
    }
    // ---- ks1 spectral
    #pragma unroll
    for (int mt=0;mt<4;mt++){
        acc[mt]=MFMA16(zA1[mt][0],tB1[0],acc[mt],0,0,0);
        acc[mt]=MFMA16(zA1[mt][0],tB1[1],acc[mt],0,0,0);
        acc[mt]=MFMA16(zA1[mt][1],tB1[0],acc[mt],0,0,0);
    }
    // ---- epilogue: tanh+split into padded LDS, then coalesced stores
    #pragma unroll
    for (int mt=0;mt<4;mt++){
        float4 cbv = *reinterpret_cast<const float4*>(cb + mt*16 + (g<<2));
        float cba[4] = {cbv.x, cbv.y, cbv.z, cbv.w};
        #pragma unroll
        for (int rg=0;rg<4;rg++){
            int o = mt*16 + (g<<2) + rg;
            float val = tanhfast(acc[mt][rg] + cba[rg]);
            u16 hh,ll; bsplit(val,hh,ll);
            so_[o*68 + colp] = (unsigned)hh | ((unsigned)ll<<16);
        }
    }
    __syncthreads();
    {
        int o = t>>2, p0 = (t&3)<<4;
        const uint4* sp = reinterpret_cast<const uint4*>(so_ + o*68 + p0);
        uint4 u0 = sp[0], u1 = sp[1], u2 = sp[2], u3 = sp[3];
        us8 h0, h1, l0, l1;
        h0[0]=(u16)u0.x; l0[0]=(u16)(u0.x>>16);
        h0[1]=(u16)u0.y; l0[1]=(u16)(u0.y>>16);
        h0[2]=(u16)u0.z; l0[2]=(u16)(u0.z>>16);
        h0[3]=(u16)u0.w; l0[3]=(u16)(u0.w>>16);
        h0[4]=(u16)u1.x; l0[4]=(u16)(u1.x>>16);
        h0[5]=(u16)u1.y; l0[5]=(u16)(u1.y>>16);
        h0[6]=(u16)u1.z; l0[6]=(u16)(u1.z>>16);
        h0[7]=(u16)u1.w; l0[7]=(u16)(u1.w>>16);
        h1[0]=(u16)u2.x; l1[0]=(u16)(u2.x>>16);
        h1[1]=(u16)u2.y; l1[1]=(u16)(u2.y>>16);
        h1[2]=(u16)u2.z; l1[2]=(u16)(u2.z>>16);
        h1[3]=(u16)u2.w; l1[3]=(u16)(u2.w>>16);
        h1[4]=(u16)u3.x; l1[4]=(u16)(u3.x>>16);
        h1[5]=(u16)u3.y; l1[5]=(u16)(u3.y>>16);
        h1[6]=(u16)u3.z; l1[6]=(u16)(u3.z>>16);
        h1[7]=(u16)u3.w; l1[7]=(u16)(u3.w>>16);
        size_t go = (size_t)o*NP + gbase + p0;
        *(us8*)(vh+go)   = h0;
        *(us8*)(vh+go+8) = h1;
        *(us8*)(vl+go)   = l0;
        *(us8*)(vl+go+8) = l1;
    }
}

// ================= FC1+FC2 =================
__global__ __launch_bounds__(256) void k_fc12(const u16* __restrict__ vh, const u16* __restrict__ vl,
    const char* __restrict__ wsb, const float* __restrict__ b1,
    const float* __restrict__ w2, const float* __restrict__ b2, float* __restrict__ out){
    __shared__ u16 sh_[4096];
    __shared__ u16 sl_[4096];
    int t = threadIdx.x, lane = t&63, wv = t>>6;
    size_t pb = (size_t)blockIdx.x*64;
    {
        int c = t>>2, p0=(t&3)<<4;
        short8 a0 = *(const short8*)(vh + (size_t)c*NP + pb + p0);
        short8 a1 = *(const short8*)(vh + (size_t)c*NP + pb + p0+8);
        short8 b0 = *(const short8*)(vl + (size_t)c*NP + pb + p0);
        short8 b1 = *(const short8*)(vl + (size_t)c*NP + pb + p0+8);
        #pragma unroll
        for (int e=0;e<8;e++){
            sh_[(p0+e)*64 + SWZ(c,p0+e)] = (u16)a0[e];
            sh_[(p0+8+e)*64 + SWZ(c,p0+8+e)] = (u16)a1[e];
            sl_[(p0+e)*64 + SWZ(c,p0+e)] = (u16)b0[e];
            sl_[(p0+8+e)*64 + SWZ(c,p0+8+e)] = (u16)b1[e];
        }
    }
    __syncthreads();
    f32x4 acc[8];
    #pragma unroll
    for (int mt=0;mt<8;mt++) acc[mt]=(f32x4){0,0,0,0};
    int colp = wv*16 + (lane&15);
    int g = lane>>4;
    const u16* f1h=(const u16*)(wsb+F1H); const u16* f1l=(const u16*)(wsb+F1L);
    #pragma unroll
    for (int ks=0;ks<2;ks++){
        bf16x8 A[8][2];
        #pragma unroll
        for (int mt=0;mt<8;mt++){
            size_t fo = (size_t)((ks*8+mt)*64 + lane)*8;
            A[mt][0] = *reinterpret_cast<const bf16x8*>(f1h+fo);
            A[mt][1] = *reinterpret_cast<const bf16x8*>(f1l+fo);
        }
        int o8 = ks*4+g;
        int so = colp*64 + ((o8 ^ (colp&7))<<3);
        bf16x8 Bh = *reinterpret_cast<const bf16x8*>(sh_+so);
        bf16x8 Bl = *reinterpret_cast<const bf16x8*>(sl_+so);
        #pragma unroll
        for (int mt=0;mt<8;mt++){
            acc[mt]=MFMA16(A[mt][0],Bh,acc[mt],0,0,0);
            acc[mt]=MFMA16(A[mt][0],Bl,acc[mt],0,0,0);
            acc[mt]=MFMA16(A[mt][1],Bh,acc[mt],0,0,0);
        }
    }
    float s = 0.f;
    #pragma unroll
    for (int mt=0;mt<8;mt++)
        #pragma unroll
        for (int rg=0;rg<4;rg++){
            int f = mt*16 + (g<<2) + rg;
            s += w2[f] * tanhfast(acc[mt][rg] + b1[f]);
        }
    s += __shfl_xor(s, 16);
    s += __shfl_xor(s, 32);
    if (lane < 16) out[pb + wv*16 + lane] = s + b2[0];
}

extern "C" void kernel_launch(void* const* d_in, const int* in_sizes, int n_in,
                              void* d_out, int out_size, void* d_ws, size_t ws_size,
                              hipStream_t stream) {
    const float* x     = (const float*)d_in[0];
    const float* fc0w  = (const float*)d_in[1];
    const float* fc0b  = (const float*)d_in[2];
    const float* sw1r  = (const float*)d_in[3];
    const float* sw1i  = (const float*)d_in[4];
    const float* sw2r  = (const float*)d_in[5];
    const float* sw2i  = (const float*)d_in[6];
    const float* convw = (const float*)d_in[7];
    const float* convb = (const float*)d_in[8];
    const float* fc1w  = (const float*)d_in[9];
    const float* fc1b  = (const float*)d_in[10];
    const float* fc2w  = (const float*)d_in[11];
    const float* fc2b  = (const float*)d_in[12];
    char* wsb = (char*)d_ws;
    float* out = (float*)d_out;

    u16* twh = (u16*)(wsb+TWH); u16* twl = (u16*)(wsb+TWL);
    u16* xwh = (u16*)(wsb+XWH); u16* xwl = (u16*)(wsb+XWL);
    float* xfP = (float*)(wsb+XFP);
    float* ypart = (float*)(wsb+YPART);
    u16* zh = (u16*)(wsb+ZH); u16* zl = (u16*)(wsb+ZL);
    u16* vh = (u16*)(wsb+VH); u16* vl = (u16*)(wsb+VL);

    k_setup<<<544, 256, 0, stream>>>(wsb, convw, fc1w);
    k_fc0<<<256, 256, 0, stream>>>(x, fc0w, fc0b, vh, vl);
    for (int L = 0; L < 4; ++L){
        size_t so = (size_t)L * 64 * 64 * 400;
        k_f1<<<512, 256, 0, stream>>>(vh, vl, twh, twl, xwh, xwl);
        k_f2<<<120, 256, 0, stream>>>(wsb, xfP);
        k_mix<<<256, 256, 0, stream>>>(sw1r+so, sw1i+so, sw2r+so, sw2i+so, xfP, ypart);
        k_mixred<<<320, 256, 0, stream>>>(ypart, wsb);
        k_i1<<<320, 128, 0, stream>>>(wsb, zh, zl);
        k_sct<<<4096, 256, 0, stream>>>(vh, vl, wsb, L, convb + (size_t)L*64, zh, zl);
    }
    k_fc12<<<4096, 256, 0, stream>>>(vh, vl, wsb, fc1b, fc2w, fc2b, out);
}

// Round 7
// 727.620 us; speedup vs baseline: 4.4171x; 1.0024x over previous
//
#include <hip/hip_runtime.h>
#include <math.h>

typedef unsigned short u16;
typedef __attribute__((ext_vector_type(8))) short short8;
typedef __attribute__((ext_vector_type(8))) short bf16x8;
typedef __attribute__((ext_vector_type(4))) unsigned short us4;
typedef __attribute__((ext_vector_type(2))) unsigned short us2;
typedef __attribute__((ext_vector_type(8))) unsigned short us8;
typedef __attribute__((ext_vector_type(4))) float f32x4;

#define NP (512*512)
#define MFMA16 __builtin_amdgcn_mfma_f32_16x16x32_bf16

// ---- workspace byte offsets (all 256-aligned) ----
#define TWH   0u
#define TWL   49152u
#define T2H   98304u
#define T2L   163840u
#define THC2H 229376u
#define THC2L 278528u
#define THS2H 327680u
#define THS2L 376832u
#define THCAH 425984u
#define THCAL 491520u
#define THSAH 557056u
#define THSAL 622592u
#define THSNH 688128u
#define THSNL 753664u
#define CFH   819200u
#define CFL   851968u
#define F1H   884736u
#define F1L   901120u
#define XWH   917504u
#define XWL   4063232u
#define XFP   7208960u
#define YPART 8028160u
#define YRH   8847360u
#define YRL   9011200u
#define YIH   9175040u
#define YIL   9338880u
#define ZH    9502720u
#define ZL    13697024u
#define VH    17891328u
#define VL    51445760u

__device__ __forceinline__ u16 brnd(float x){
    unsigned u = __float_as_uint(x);
    unsigned r = (u + 0x7FFFu + ((u>>16)&1u)) >> 16;
    return (u16)r;
}
__device__ __forceinline__ float fbf(u16 h){ return __uint_as_float(((unsigned)h)<<16); }
__device__ __forceinline__ void bsplit(float x, u16& h, u16& l){
    h = brnd(x); l = brnd(x - fbf(h));
}
__device__ __forceinline__ float tanhfast(float x){
    x = fminf(10.f, fmaxf(-10.f, x));
    float e = __expf(2.f*x);
    return (e-1.f)/(e+1.f);
}

// ================= setup: tables + weight frags =================
__global__ void k_setup(char* wsb, const float* __restrict__ convw, const float* __restrict__ fc1w){
    int i = blockIdx.x*256 + threadIdx.x;
    const float c2pi = 6.283185307179586f/512.0f;
    if (i < 24576){                         // TW
        int e=i&7, lane=(i>>3)&63, g=i>>9; int nt=g%3;
        int k = (g/3)*32 + ((lane>>4)<<3) + e;
        int n = nt*16 + (lane&15);
        float v=0.f;
        if(n<40){int kx=n>>1; float a=c2pi*(float)((kx*k)&511); v=(n&1)?-sinf(a):cosf(a);}
        u16 h,l; bsplit(v,h,l);
        ((u16*)(wsb+TWH))[i]=h; ((u16*)(wsb+TWL))[i]=l;
    } else if (i < 57344){                  // T2
        int j2=i-24576;
        int e=j2&7, lane=(j2>>3)&63, g=j2>>9; int ks=g&1, wt=g>>1;
        int j = ks*32 + ((lane>>4)<<3) + e;
        int w = wt*16 + (lane&15);
        float v=0.f;
        if(j<40){int kx=j>>1; float a=c2pi*(float)((kx*w)&511); v=(j&1)?-sinf(a):cosf(a);}
        u16 h,l; bsplit(v,h,l);
        ((u16*)(wsb+T2H))[j2]=h; ((u16*)(wsb+T2L))[j2]=l;
    } else if (i < 81920){                  // f2 A [m48][h512]
        int j2 = i-57344;
        int m=j2>>9, hh=j2&511;
        float vc=0.f,vs=0.f;
        if(m<40){int ky=(m<20)?m:(472+m); float a=c2pi*(float)((ky*hh)&511); vc=cosf(a); vs=sinf(a);}
        u16 h,l;
        bsplit(vc,h,l); ((u16*)(wsb+THC2H))[j2]=h; ((u16*)(wsb+THC2L))[j2]=l;
        bsplit(vs,h,l); ((u16*)(wsb+THS2H))[j2]=h; ((u16*)(wsb+THS2L))[j2]=l;
    } else if (i < 114688){                 // i1 A [h512][m64]
        int j2 = i-81920;
        int hh=j2>>6, m=j2&63;
        float vc=0.f,vs=0.f;
        if(m<40){int ky=(m<20)?m:(472+m); float a=c2pi*(float)((ky*hh)&511); vc=cosf(a); vs=sinf(a);}
        u16 h,l;
        bsplit(vc,h,l);  ((u16*)(wsb+THCAH))[j2]=h; ((u16*)(wsb+THCAL))[j2]=l;
        bsplit(vs,h,l);  ((u16*)(wsb+THSAH))[j2]=h; ((u16*)(wsb+THSAL))[j2]=l;
        bsplit(-vs,h,l); ((u16*)(wsb+THSNH))[j2]=h; ((u16*)(wsb+THSNL))[j2]=l;
    } else {                                // weight frags
        int j = i - 114688;
        if (j < 16384){
            int e=j&7, lane=(j>>3)&63, g=j>>9;
            int mt=g&3, ks=(g>>2)&1, L=g>>3;
            int o = mt*16+(lane&15), c = ks*32+((lane>>4)<<3)+e;
            float v = convw[L*4096 + o*64 + c];
            u16 h,l; bsplit(v,h,l);
            ((u16*)(wsb+CFH))[j]=h; ((u16*)(wsb+CFL))[j]=l;
        } else {
            int j2=j-16384;
            int e=j2&7, lane=(j2>>3)&63, g=j2>>9;
            int mt=g&7, ks=g>>3;
            int f = mt*16+(lane&15), c = ks*32+((lane>>4)<<3)+e;
            float v = fc1w[f*64+c];
            u16 h,l; bsplit(v,h,l);
            ((u16*)(wsb+F1H))[j2]=h; ((u16*)(wsb+F1L))[j2]=l;
        }
    }
}

// ================= fc0 =================
__global__ __launch_bounds__(256) void k_fc0(const float* __restrict__ x,
    const float* __restrict__ w, const float* __restrict__ b,
    u16* __restrict__ vh, u16* __restrict__ vl){
    __shared__ float xs[1024*3];
    __shared__ float ws3[192], bs[64];
    int t = threadIdx.x;
    size_t pb = (size_t)blockIdx.x*1024;
    const float4* xg = (const float4*)(x + pb*3);
    float4* xs4 = (float4*)xs;
    #pragma unroll
    for (int k=0;k<3;k++) xs4[t + k*256] = xg[t + k*256];
    if (t<192) ws3[t]=w[t];
    if (t<64) bs[t]=b[t];
    __syncthreads();
    int p0 = t*4;
    float X0[4],X1[4],X2[4];
    #pragma unroll
    for(int e=0;e<4;e++){X0[e]=xs[(p0+e)*3];X1[e]=xs[(p0+e)*3+1];X2[e]=xs[(p0+e)*3+2];}
    for (int c=0;c<64;c++){
        float w0=ws3[c*3],w1=ws3[c*3+1],w2=ws3[c*3+2],bc=bs[c];
        us4 sh, sl;
        #pragma unroll
        for(int e=0;e<4;e++){
            float v = w0*X0[e]+w1*X1[e]+w2*X2[e]+bc;
            u16 hh,ll; bsplit(v,hh,ll); sh[e]=hh; sl[e]=ll;
        }
        *(us4*)(vh + (size_t)c*NP + pb + p0) = sh;
        *(us4*)(vl + (size_t)c*NP + pb + p0) = sl;
    }
}

// ================= F1: 2 row-tiles per wave, shared B =================
__global__ __launch_bounds__(256) void k_f1(const u16* __restrict__ vh, const u16* __restrict__ vl,
    const u16* __restrict__ twh, const u16* __restrict__ twl,
    u16* __restrict__ xwh, u16* __restrict__ xwl){
    int lane = threadIdx.x & 63, wv = threadIdx.x >> 6;
    int r0a = blockIdx.x*128 + wv*16;     // tile0
    int r1a = r0a + 64;                    // tile1
    int rl = lane&15;
    const u16* ah0 = vh + (size_t)(r0a+rl)*512 + ((lane>>4)<<3);
    const u16* al0 = vl + (size_t)(r0a+rl)*512 + ((lane>>4)<<3);
    const u16* ah1 = vh + (size_t)(r1a+rl)*512 + ((lane>>4)<<3);
    const u16* al1 = vl + (size_t)(r1a+rl)*512 + ((lane>>4)<<3);
    f32x4 acc[2][3];
    #pragma unroll
    for (int tt = 0; tt < 2; ++tt)
        #pragma unroll
        for (int nt = 0; nt < 3; ++nt) acc[tt][nt] = (f32x4){0.f,0.f,0.f,0.f};
    #pragma unroll 2
    for (int kk = 0; kk < 16; ++kk){
        bf16x8 Bh[3], Bl[3];
        #pragma unroll
        for (int nt = 0; nt < 3; ++nt){
            size_t bo = ((size_t)(kk*3+nt)*64 + lane)*8;
            Bh[nt] = *reinterpret_cast<const bf16x8*>(twh + bo);
            Bl[nt] = *reinterpret_cast<const bf16x8*>(twl + bo);
        }
        bf16x8 Ah0 = *reinterpret_cast<const bf16x8*>(ah0 + kk*32);
        bf16x8 Al0 = *reinterpret_cast<const bf16x8*>(al0 + kk*32);
        bf16x8 Ah1 = *reinterpret_cast<const bf16x8*>(ah1 + kk*32);
        bf16x8 Al1 = *reinterpret_cast<const bf16x8*>(al1 + kk*32);
        #pragma unroll
        for (int nt = 0; nt < 3; ++nt){
            acc[0][nt] = MFMA16(Ah0, Bh[nt], acc[0][nt], 0,0,0);
            acc[0][nt] = MFMA16(Ah0, Bl[nt], acc[0][nt], 0,0,0);
            acc[0][nt] = MFMA16(Al0, Bh[nt], acc[0][nt], 0,0,0);
            acc[1][nt] = MFMA16(Ah1, Bh[nt], acc[1][nt], 0,0,0);
            acc[1][nt] = MFMA16(Ah1, Bl[nt], acc[1][nt], 0,0,0);
            acc[1][nt] = MFMA16(Al1, Bh[nt], acc[1][nt], 0,0,0);
        }
    }
    int colj = lane&15;
    #pragma unroll
    for (int tt = 0; tt < 2; ++tt){
        int r0 = (tt ? r1a : r0a) + ((lane>>4)<<2);
        int c = r0>>9, h0 = r0&511;
        #pragma unroll
        for (int nt = 0; nt < 3; ++nt){
            int j = nt*16 + colj;
            us4 uh, ul;
            #pragma unroll
            for (int rg = 0; rg < 4; ++rg){
                u16 hh,ll; bsplit(acc[tt][nt][rg],hh,ll); uh[rg]=hh; ul[rg]=ll;
            }
            size_t off = ((size_t)j*64 + c)*512 + h0;
            *(us4*)(xwh + off) = uh;
            *(us4*)(xwl + off) = ul;
        }
    }
}

// ================= F2: one mt per block =================
__global__ __launch_bounds__(256) void k_f2(const char* __restrict__ wsb, float* __restrict__ xfP){
    int b = blockIdx.x;             // 120 = kx*6 + mt*2 + kh
    int kx = b/6, r = b%6, mt = r>>1, kh = r&1;
    int lane = threadIdx.x&63, wv = threadIdx.x>>6;
    const u16* thch=(const u16*)(wsb+THC2H); const u16* thcl=(const u16*)(wsb+THC2L);
    const u16* thsh=(const u16*)(wsb+THS2H); const u16* thsl=(const u16*)(wsb+THS2L);
    const u16* xwh=(const u16*)(wsb+XWH);   const u16* xwl=(const u16*)(wsb+XWL);
    f32x4 aA=(f32x4){0,0,0,0}, aB=aA, aC=aA, aD=aA;
    int g8 = (lane>>4)<<3;
    int mrow = lane&15;
    int cB = wv*16 + (lane&15);
    size_t bre = ((size_t)(2*kx)*64 + cB)*512;
    size_t bim = ((size_t)(2*kx+1)*64 + cB)*512;
    for (int kk = kh*8; kk < kh*8+8; ++kk){
        int hof = kk*32 + g8;
        bf16x8 XRh = *reinterpret_cast<const bf16x8*>(xwh + bre + hof);
        bf16x8 XRl = *reinterpret_cast<const bf16x8*>(xwl + bre + hof);
        bf16x8 XIh = *reinterpret_cast<const bf16x8*>(xwh + bim + hof);
        bf16x8 XIl = *reinterpret_cast<const bf16x8*>(xwl + bim + hof);
        size_t ao = (size_t)(mt*16+mrow)*512 + hof;
        bf16x8 Ch = *reinterpret_cast<const bf16x8*>(thch+ao);
        bf16x8 Cl = *reinterpret_cast<const bf16x8*>(thcl+ao);
        bf16x8 Sh = *reinterpret_cast<const bf16x8*>(thsh+ao);
        bf16x8 Sl = *reinterpret_cast<const bf16x8*>(thsl+ao);
        aA=MFMA16(Ch,XRh,aA,0,0,0); aA=MFMA16(Ch,XRl,aA,0,0,0); aA=MFMA16(Cl,XRh,aA,0,0,0);
        aB=MFMA16(Sh,XIh,aB,0,0,0); aB=MFMA16(Sh,XIl,aB,0,0,0); aB=MFMA16(Sl,XIh,aB,0,0,0);
        aC=MFMA16(Ch,XIh,aC,0,0,0); aC=MFMA16(Ch,XIl,aC,0,0,0); aC=MFMA16(Cl,XIh,aC,0,0,0);
        aD=MFMA16(Sh,XRh,aD,0,0,0); aD=MFMA16(Sh,XRl,aD,0,0,0); aD=MFMA16(Sl,XRh,aD,0,0,0);
    }
    #pragma unroll
    for (int rg=0;rg<4;rg++){
        int m = mt*16 + ((lane>>4)<<2) + rg;
        if (m < 40){
            float re = aA[rg]+aB[rg];
            float im = aC[rg]-aD[rg];
            size_t xo = ((size_t)kh*64 + cB)*1600 + (size_t)(m*20+kx)*2;
            xfP[xo] = re; xfP[xo+1] = im;
        }
    }
}

// ================= MIX =================
__global__ __launch_bounds__(256) void k_mix(const float* __restrict__ w1r,const float* __restrict__ w1i,
    const float* __restrict__ w2r,const float* __restrict__ w2i,
    const float* __restrict__ xfP, float* __restrict__ ypart){
    __shared__ float xs[2][800];
    int b = blockIdx.x;
    int iseg = b>>7, half = (b>>6)&1, o = b&63;
    int t = threadIdx.x;
    const float* wr = (half? w2r : w1r) + o*400;
    const float* wi = (half? w2i : w1i) + o*400;
    const float* xp0 = xfP + half*800;
    const float* xp1 = xfP + (size_t)64*1600 + half*800;
    int i0 = iseg*32;
    {
        const float* a = xp0 + (size_t)i0*1600; const float* c = xp1 + (size_t)i0*1600;
        xs[0][t]=a[t]+c[t]; xs[0][t+256]=a[t+256]+c[t+256];
        if (t<288) xs[0][t+512]=a[t+512]+c[t+512];
    }
    int p1 = t, p2 = t+256; bool has2 = (p2<400);
    float ar1=0,ai1=0,ar2=0,ai2=0;
    size_t wof = (size_t)i0*25600;
    float wAr1=wr[wof+p1], wAi1=wi[wof+p1];
    float wAr2=0,wAi2=0;
    if(has2){ wAr2=wr[wof+p2]; wAi2=wi[wof+p2]; }
    __syncthreads();
    for (int ii=0; ii<32; ++ii){
        int cur = ii&1;
        if (ii<31){
            int i = i0+ii+1;
            const float* a = xp0 + (size_t)i*1600; const float* c = xp1 + (size_t)i*1600;
            float* d = xs[cur^1];
            d[t]=a[t]+c[t]; d[t+256]=a[t+256]+c[t+256];
            if(t<288) d[t+512]=a[t+512]+c[t+512];
        }
        float wBr1=0,wBi1=0,wBr2=0,wBi2=0;
        if (ii<31){
            size_t wo2 = (size_t)(i0+ii+1)*25600;
            wBr1=wr[wo2+p1]; wBi1=wi[wo2+p1];
            if(has2){ wBr2=wr[wo2+p2]; wBi2=wi[wo2+p2]; }
        }
        float xr=xs[cur][2*p1], xi=xs[cur][2*p1+1];
        ar1 += xr*wAr1 - xi*wAi1; ai1 += xr*wAi1 + xi*wAr1;
        if (has2){
            float xr2=xs[cur][2*p2], xi2=xs[cur][2*p2+1];
            ar2 += xr2*wAr2 - xi2*wAi2; ai2 += xr2*wAi2 + xi2*wAr2;
        }
        wAr1=wBr1; wAi1=wBi1; wAr2=wBr2; wAi2=wBi2;
        __syncthreads();
    }
    int mode1 = half*400 + p1;
    size_t y1 = ((size_t)(iseg*800 + mode1)*64 + o)*2;
    ypart[y1]=ar1; ypart[y1+1]=ai1;
    if (has2){
        int mode2 = half*400 + p2;
        size_t y2 = ((size_t)(iseg*800 + mode2)*64 + o)*2;
        ypart[y2]=ar2; ypart[y2+1]=ai2;
    }
}

// ================= MIXRED =================
__global__ void k_mixred(const float* __restrict__ ypart, char* wsb){
    int g = blockIdx.x*256+threadIdx.x;
    int m = g&63, o=(g>>6)&63, kx=g>>12;
    float vr=0.f, vi=0.f;
    if (m<40){
        int mode = m*20+kx;
        size_t i0 = ((size_t)mode*64+o)*2;
        size_t i1 = ((size_t)(800+mode)*64+o)*2;
        float sc = (kx==0?1.f:2.f)*(1.f/262144.f);
        vr = (ypart[i0]+ypart[i1])*sc;
        vi = (ypart[i0+1]+ypart[i1+1])*sc;
    }
    u16 h,l; size_t yo = ((size_t)kx*64+o)*64+m;
    bsplit(vr,h,l); ((u16*)(wsb+YRH))[yo]=h; ((u16*)(wsb+YRL))[yo]=l;
    bsplit(vi,h,l); ((u16*)(wsb+YIH))[yo]=h; ((u16*)(wsb+YIL))[yo]=l;
}

// ================= I1: 128-thr blocks =================
__global__ __launch_bounds__(128) void k_i1(const char* __restrict__ wsb,
    u16* __restrict__ zh, u16* __restrict__ zl){
    int b = blockIdx.x; int kx = b>>4, hb = b&15;
    int lane = threadIdx.x&63, wv = threadIdx.x>>6;
    const u16* thcAh=(const u16*)(wsb+THCAH); const u16* thcAl=(const u16*)(wsb+THCAL);
    const u16* thsAh=(const u16*)(wsb+THSAH); const u16* thsAl=(const u16*)(wsb+THSAL);
    const u16* thsnh=(const u16*)(wsb+THSNH); const u16* thsnl=(const u16*)(wsb+THSNL);
    const u16* yrh=(const u16*)(wsb+YRH); const u16* yrl=(const u16*)(wsb+YRL);
    const u16* yih=(const u16*)(wsb+YIH); const u16* yil=(const u16*)(wsb+YIL);
    f32x4 aR[4], aI[4];
    #pragma unroll
    for(int nt=0;nt<4;nt++){aR[nt]=(f32x4){0,0,0,0}; aI[nt]=aR[nt];}
    int g8 = (lane>>4)<<3;
    int hrow = hb*32 + wv*16 + (lane&15);
    #pragma unroll
    for (int ks=0; ks<2; ++ks){
        size_t ao = (size_t)hrow*64 + ks*32 + g8;
        bf16x8 Ch=*reinterpret_cast<const bf16x8*>(thcAh+ao);
        bf16x8 Cl=*reinterpret_cast<const bf16x8*>(thcAl+ao);
        bf16x8 Sh=*reinterpret_cast<const bf16x8*>(thsAh+ao);
        bf16x8 Sl=*reinterpret_cast<const bf16x8*>(thsAl+ao);
        bf16x8 Nh=*reinterpret_cast<const bf16x8*>(thsnh+ao);
        bf16x8 Nl=*reinterpret_cast<const bf16x8*>(thsnl+ao);
        #pragma unroll
        for (int nt=0; nt<4; ++nt){
            int o = nt*16+(lane&15);
            size_t bo = ((size_t)kx*64+o)*64 + ks*32 + g8;
            bf16x8 Rh=*reinterpret_cast<const bf16x8*>(yrh+bo);
            bf16x8 Rl=*reinterpret_cast<const bf16x8*>(yrl+bo);
            bf16x8 Ih=*reinterpret_cast<const bf16x8*>(yih+bo);
            bf16x8 Il=*reinterpret_cast<const bf16x8*>(yil+bo);
            aR[nt]=MFMA16(Ch,Rh,aR[nt],0,0,0); aR[nt]=MFMA16(Ch,Rl,aR[nt],0,0,0); aR[nt]=MFMA16(Cl,Rh,aR[nt],0,0,0);
            aR[nt]=MFMA16(Nh,Ih,aR[nt],0,0,0); aR[nt]=MFMA16(Nh,Il,aR[nt],0,0,0); aR[nt]=MFMA16(Nl,Ih,aR[nt],0,0,0);
            aI[nt]=MFMA16(Sh,Rh,aI[nt],0,0,0); aI[nt]=MFMA16(Sh,Rl,aI[nt],0,0,0); aI[nt]=MFMA16(Sl,Rh,aI[nt],0,0,0);
            aI[nt]=MFMA16(Ch,Ih,aI[nt],0,0,0); aI[nt]=MFMA16(Ch,Il,aI[nt],0,0,0); aI[nt]=MFMA16(Cl,Ih,aI[nt],0,0,0);
        }
    }
    #pragma unroll
    for (int nt=0;nt<4;nt++)
        #pragma unroll
        for (int rg=0;rg<4;rg++){
            int h = hb*32 + wv*16 + ((lane>>4)<<2) + rg;
            int o = nt*16+(lane&15);
            size_t za = ((size_t)h*64+o)*64 + 2*kx;
            u16 h1,l1,h2,l2;
            bsplit(aR[nt][rg],h1,l1); bsplit(aI[nt][rg],h2,l2);
            us2 sh={h1,h2}, sl={l1,l2};
            *(us2*)(zh+za)=sh; *(us2*)(zl+za)=sl;
        }
}

// ================= SCT =================
#define SWZ(c,p) ((c) ^ (((p)&7)<<3))
__global__ __launch_bounds__(256) void k_sct(u16* __restrict__ vh, u16* __restrict__ vl,
    const char* __restrict__ wsb, int L, const float* __restrict__ cb,
    const u16* __restrict__ zh, const u16* __restrict__ zl){
    // union: sh_(8KB)+sl_(8KB) live during MFMA phase; so_(17KB) reuses the
    // same space for the epilogue transpose (separated by __syncthreads).
    __shared__ __align__(16) char smem[17408];
    u16* sh_ = (u16*)smem;
    u16* sl_ = (u16*)(smem + 8192);
    unsigned* so_ = (unsigned*)smem;
    int t = threadIdx.x, lane = t&63, wv = t>>6;
    int h = blockIdx.x>>3, pb = (blockIdx.x&7)<<6;
    size_t gbase = (size_t)h*512 + pb;
    const u16* cfh=(const u16*)(wsb+CFH); const u16* cfl=(const u16*)(wsb+CFL);
    const u16* t2h=(const u16*)(wsb+T2H); const u16* t2l=(const u16*)(wsb+T2L);
    int g = lane>>4;
    int colp = wv*16 + (lane&15);
    int wt = (pb>>4) + wv;
    // ---- stage loads issue first
    int cst = t>>2, p0s=(t&3)<<4;
    short8 a0 = *(const short8*)(vh + (size_t)cst*NP + gbase + p0s);
    short8 a1 = *(const short8*)(vh + (size_t)cst*NP + gbase + p0s+8);
    short8 b0 = *(const short8*)(vl + (size_t)cst*NP + gbase + p0s);
    short8 b1 = *(const short8*)(vl + (size_t)cst*NP + gbase + p0s+8);
    // ---- ks0 frag loads in flight
    bf16x8 cA0[4][2], zA0[4][2], tB0[2];
    #pragma unroll
    for (int mt=0;mt<4;mt++){
        size_t fo = (size_t)(((L*2+0)*4+mt)*64 + lane)*8;
        cA0[mt][0] = *reinterpret_cast<const bf16x8*>(cfh+fo);
        cA0[mt][1] = *reinterpret_cast<const bf16x8*>(cfl+fo);
        size_t ao = (((size_t)h*64 + mt*16+(lane&15))*64) + (g<<3);
        zA0[mt][0] = *reinterpret_cast<const bf16x8*>(zh+ao);
        zA0[mt][1] = *reinterpret_cast<const bf16x8*>(zl+ao);
    }
    {
        size_t bo = ((size_t)(wt*2+0)*64 + lane)*8;
        tB0[0] = *reinterpret_cast<const bf16x8*>(t2h+bo);
        tB0[1] = *reinterpret_cast<const bf16x8*>(t2l+bo);
    }
    // ---- stage to LDS (swizzled transpose)
    #pragma unroll
    for (int e=0;e<8;e++){
        sh_[(p0s+e)*64 + SWZ(cst,p0s+e)] = (u16)a0[e];
        sh_[(p0s+8+e)*64 + SWZ(cst,p0s+8+e)] = (u16)a1[e];
        sl_[(p0s+e)*64 + SWZ(cst,p0s+e)] = (u16)b0[e];
        sl_[(p0s+8+e)*64 + SWZ(cst,p0s+8+e)] = (u16)b1[e];
    }
    __syncthreads();
    f32x4 acc[4];
    #pragma unroll
    for (int mt=0;mt<4;mt++) acc[mt]=(f32x4){0,0,0,0};
    // ---- ks0 conv
    {
        int so = colp*64 + ((g ^ (colp&7))<<3);
        bf16x8 Bh = *reinterpret_cast<const bf16x8*>(sh_+so);
        bf16x8 Bl = *reinterpret_cast<const bf16x8*>(sl_+so);
        #pragma unroll
        for (int mt=0;mt<4;mt++){
            acc[mt]=MFMA16(cA0[mt][0],Bh,acc[mt],0,0,0);
            acc[mt]=MFMA16(cA0[mt][0],Bl,acc[mt],0,0,0);
            acc[mt]=MFMA16(cA0[mt][1],Bh,acc[mt],0,0,0);
        }
    }
    // ---- issue ks1 loads
    bf16x8 cA1[4][2], zA1[4][2], tB1[2];
    #pragma unroll
    for (int mt=0;mt<4;mt++){
        size_t fo = (size_t)(((L*2+1)*4+mt)*64 + lane)*8;
        cA1[mt][0] = *reinterpret_cast<const bf16x8*>(cfh+fo);
        cA1[mt][1] = *reinterpret_cast<const bf16x8*>(cfl+fo);
        size_t ao = (((size_t)h*64 + mt*16+(lane&15))*64) + 32 + (g<<3);
        zA1[mt][0] = *reinterpret_cast<const bf16x8*>(zh+ao);
        zA1[mt][1] = *reinterpret_cast<const bf16x8*>(zl+ao);
    }
    {
        size_t bo = ((size_t)(wt*2+1)*64 + lane)*8;
        tB1[0] = *reinterpret_cast<const bf16x8*>(t2h+bo);
        tB1[1] = *reinterpret_cast<const bf16x8*>(t2l+bo);
    }
    // ---- ks0 spectral
    #pragma unroll
    for (int mt=0;mt<4;mt++){
        acc[mt]=MFMA16(zA0[mt][0],tB0[0],acc[mt],0,0,0);
        acc[mt]=MFMA16(zA0[mt][0],tB0[1],acc[mt],0,0,0);
        acc[mt]=MFMA16(zA0[mt][1],tB0[0],acc[mt],0,0,0);
    }
    // ---- ks1 conv
    {
        int so = colp*64 + (((4+g) ^ (colp&7))<<3);
        bf16x8 Bh = *reinterpret_cast<const bf16x8*>(sh_+so);
        bf16x8 Bl = *reinterpret_cast<const bf16x8*>(sl_+so);
        #pragma unroll
        for (int mt=0;mt<4;mt++){
            acc[mt]=MFMA16(cA1[mt][0],Bh,acc[mt],0,0,0);
            acc[mt]=MFMA16(cA1[mt][0],Bl,acc[mt],0,0,0);
            acc[mt]=MFMA16(cA1[mt][1],Bh,acc[mt],0,0,0);
        }
    }
    // ---- ks1 spectral
    #pragma unroll
    for (int mt=0;mt<4;mt++){
        acc[mt]=MFMA16(zA1[mt][0],tB1[0],acc[mt],0,0,0);
        acc[mt]=MFMA16(zA1[mt][0],tB1[1],acc[mt],0,0,0);
        acc[mt]=MFMA16(zA1[mt][1],tB1[0],acc[mt],0,0,0);
    }
    // ---- all LDS frag reads done; reuse smem as epilogue buffer
    __syncthreads();
    #pragma unroll
    for (int mt=0;mt<4;mt++){
        float4 cbv = *reinterpret_cast<const float4*>(cb + mt*16 + (g<<2));
        float cba[4] = {cbv.x, cbv.y, cbv.z, cbv.w};
        #pragma unroll
        for (int rg=0;rg<4;rg++){
            int o = mt*16 + (g<<2) + rg;
            float val = tanhfast(acc[mt][rg] + cba[rg]);
            u16 hh,ll; bsplit(val,hh,ll);
            so_[o*68 + colp] = (unsigned)hh | ((unsigned)ll<<16);
        }
    }
    __syncthreads();
    {
        int o = t>>2, p0 = (t&3)<<4;
        const uint4* sp = reinterpret_cast<const uint4*>(so_ + o*68 + p0);
        uint4 u0 = sp[0], u1 = sp[1], u2 = sp[2], u3 = sp[3];
        us8 h0, h1, l0, l1;
        h0[0]=(u16)u0.x; l0[0]=(u16)(u0.x>>16);
        h0[1]=(u16)u0.y; l0[1]=(u16)(u0.y>>16);
        h0[2]=(u16)u0.z; l0[2]=(u16)(u0.z>>16);
        h0[3]=(u16)u0.w; l0[3]=(u16)(u0.w>>16);
        h0[4]=(u16)u1.x; l0[4]=(u16)(u1.x>>16);
        h0[5]=(u16)u1.y; l0[5]=(u16)(u1.y>>16);
        h0[6]=(u16)u1.z; l0[6]=(u16)(u1.z>>16);
        h0[7]=(u16)u1.w; l0[7]=(u16)(u1.w>>16);
        h1[0]=(u16)u2.x; l1[0]=(u16)(u2.x>>16);
        h1[1]=(u16)u2.y; l1[1]=(u16)(u2.y>>16);
        h1[2]=(u16)u2.z; l1[2]=(u16)(u2.z>>16);
        h1[3]=(u16)u2.w; l1[3]=(u16)(u2.w>>16);
        h1[4]=(u16)u3.x; l1[4]=(u16)(u3.x>>16);
        h1[5]=(u16)u3.y; l1[5]=(u16)(u3.y>>16);
        h1[6]=(u16)u3.z; l1[6]=(u16)(u3.z>>16);
        h1[7]=(u16)u3.w; l1[7]=(u16)(u3.w>>16);
        size_t go = (size_t)o*NP + gbase + p0;
        *(us8*)(vh+go)   = h0;
        *(us8*)(vh+go+8) = h1;
        *(us8*)(vl+go)   = l0;
        *(us8*)(vl+go+8) = l1;
    }
}

// ================= FC1+FC2 =================
__global__ __launch_bounds__(256) void k_fc12(const u16* __restrict__ vh, const u16* __restrict__ vl,
    const char* __restrict__ wsb, const float* __restrict__ b1,
    const float* __restrict__ w2, const float* __restrict__ b2, float* __restrict__ out){
    __shared__ u16 sh_[4096];
    __shared__ u16 sl_[4096];
    int t = threadIdx.x, lane = t&63, wv = t>>6;
    size_t pb = (size_t)blockIdx.x*64;
    {
        int c = t>>2, p0=(t&3)<<4;
        short8 a0 = *(const short8*)(vh + (size_t)c*NP + pb + p0);
        short8 a1 = *(const short8*)(vh + (size_t)c*NP + pb + p0+8);
        short8 b0 = *(const short8*)(vl + (size_t)c*NP + pb + p0);
        short8 b1 = *(const short8*)(vl + (size_t)c*NP + pb + p0+8);
        #pragma unroll
        for (int e=0;e<8;e++){
            sh_[(p0+e)*64 + SWZ(c,p0+e)] = (u16)a0[e];
            sh_[(p0+8+e)*64 + SWZ(c,p0+8+e)] = (u16)a1[e];
            sl_[(p0+e)*64 + SWZ(c,p0+e)] = (u16)b0[e];
            sl_[(p0+8+e)*64 + SWZ(c,p0+8+e)] = (u16)b1[e];
        }
    }
    __syncthreads();
    f32x4 acc[8];
    #pragma unroll
    for (int mt=0;mt<8;mt++) acc[mt]=(f32x4){0,0,0,0};
    int colp = wv*16 + (lane&15);
    int g = lane>>4;
    const u16* f1h=(const u16*)(wsb+F1H); const u16* f1l=(const u16*)(wsb+F1L);
    #pragma unroll
    for (int ks=0;ks<2;ks++){
        bf16x8 A[8][2];
        #pragma unroll
        for (int mt=0;mt<8;mt++){
            size_t fo = (size_t)((ks*8+mt)*64 + lane)*8;
            A[mt][0] = *reinterpret_cast<const bf16x8*>(f1h+fo);
            A[mt][1] = *reinterpret_cast<const bf16x8*>(f1l+fo);
        }
        int o8 = ks*4+g;
        int so = colp*64 + ((o8 ^ (colp&7))<<3);
        bf16x8 Bh = *reinterpret_cast<const bf16x8*>(sh_+so);
        bf16x8 Bl = *reinterpret_cast<const bf16x8*>(sl_+so);
        #pragma unroll
        for (int mt=0;mt<8;mt++){
            acc[mt]=MFMA16(A[mt][0],Bh,acc[mt],0,0,0);
            acc[mt]=MFMA16(A[mt][0],Bl,acc[mt],0,0,0);
            acc[mt]=MFMA16(A[mt][1],Bh,acc[mt],0,0,0);
        }
    }
    float s = 0.f;
    #pragma unroll
    for (int mt=0;mt<8;mt++)
        #pragma unroll
        for (int rg=0;rg<4;rg++){
            int f = mt*16 + (g<<2) + rg;
            s += w2[f] * tanhfast(acc[mt][rg] + b1[f]);
        }
    s += __shfl_xor(s, 16);
    s += __shfl_xor(s, 32);
    if (lane < 16) out[pb + wv*16 + lane] = s + b2[0];
}

extern "C" void kernel_launch(void* const* d_in, const int* in_sizes, int n_in,
                              void* d_out, int out_size, void* d_ws, size_t ws_size,
                              hipStream_t stream) {
    const float* x     = (const float*)d_in[0];
    const float* fc0w  = (const float*)d_in[1];
    const float* fc0b  = (const float*)d_in[2];
    const float* sw1r  = (const float*)d_in[3];
    const float* sw1i  = (const float*)d_in[4];
    const float* sw2r  = (const float*)d_in[5];
    const float* sw2i  = (const float*)d_in[6];
    const float* convw = (const float*)d_in[7];
    const float* convb = (const float*)d_in[8];
    const float* fc1w  = (const float*)d_in[9];
    const float* fc1b  = (const float*)d_in[10];
    const float* fc2w  = (const float*)d_in[11];
    const float* fc2b  = (const float*)d_in[12];
    char* wsb = (char*)d_ws;
    float* out = (float*)d_out;

    u16* twh = (u16*)(wsb+TWH); u16* twl = (u16*)(wsb+TWL);
    u16* xwh = (u16*)(wsb+XWH); u16* xwl = (u16*)(wsb+XWL);
    float* xfP = (float*)(wsb+XFP);
    float* ypart = (float*)(wsb+YPART);
    u16* zh = (u16*)(wsb+ZH); u16* zl = (u16*)(wsb+ZL);
    u16* vh = (u16*)(wsb+VH); u16* vl = (u16*)(wsb+VL);

    k_setup<<<544, 256, 0, stream>>>(wsb, convw, fc1w);
    k_fc0<<<256, 256, 0, stream>>>(x, fc0w, fc0b, vh, vl);
    for (int L = 0; L < 4; ++L){
        size_t so = (size_t)L * 64 * 64 * 400;
        k_f1<<<256, 256, 0, stream>>>(vh, vl, twh, twl, xwh, xwl);
        k_f2<<<120, 256, 0, stream>>>(wsb, xfP);
        k_mix<<<256, 256, 0, stream>>>(sw1r+so, sw1i+so, sw2r+so, sw2i+so, xfP, ypart);
        k_mixred<<<320, 256, 0, stream>>>(ypart, wsb);
        k_i1<<<320, 128, 0, stream>>>(wsb, zh, zl);
        k_sct<<<4096, 256, 0, stream>>>(vh, vl, wsb, L, convb + (size_t)L*64, zh, zl);
    }
    k_fc12<<<4096, 256, 0, stream>>>(vh, vl, wsb, fc1b, fc2w, fc2b, out);
}